// Round 1
// baseline (357.523 us; speedup 1.0000x reference)
//
#include <hip/hip_runtime.h>

// ---------------- problem constants ----------------
#define NN    1024   // nodes
#define CC    128    // channels
#define NELEM 10
#define NQ3   816    // C(18,3) sorted triples over 16
#define NQ2   136    // sorted pairs
#define NQ    968    // 816 + 136 + 16

// ---------------- workspace layout (bytes) ----------------
#define USYM3_OFF 0          // float[4][816][32]  = 417792
#define USYM2_OFF 417792     // float[4][136][16]  = 34816  -> 452608
#define NL_OFF    452608     // int[10][1024]      = 40960  -> 493568
#define CNT_OFF   493568     // int[10]
#define CALL_OFF  524288     // float4[1280][968]  = 19824640 -> 20348928
#define F_OFF     20447232   // float4[1024][128]  = 2097152  -> 22544384

__device__ __constant__ int d_OFF2[16] = {0,16,31,45,58,70,81,91,100,108,115,121,126,130,133,135};
__device__ __constant__ int d_OFF3[16] = {0,136,256,361,452,530,596,651,696,732,760,781,796,806,812,815};

// ---- build symmetrized cubic U:  usym3[Lout][q3][32] (p padded to 32) ----
__global__ void k_usym3(const float* __restrict__ U3_0, const float* __restrict__ U3_1,
                        float* __restrict__ usym3) {
    int tid = blockIdx.x * 256 + threadIdx.x;
    if (tid >= 4 * 4096) return;
    int Lout = tid >> 12;
    int r = tid & 4095;
    int a = r >> 8, b = (r >> 4) & 15, m = r & 15;
    if (a > b || b > m) return;                       // only sorted triples
    int q = d_OFF3[a] + (d_OFF2[b] - d_OFF2[a]) + (m - b);
    const float* U = (Lout == 0) ? U3_0 : U3_1;
    int L = (Lout == 0) ? 0 : (Lout - 1);
    int P[6][3] = {{a,b,m},{a,m,b},{b,a,m},{b,m,a},{m,a,b},{m,b,a}};
    float s[30];
#pragma unroll
    for (int p = 0; p < 30; ++p) s[p] = 0.f;
    for (int t = 0; t < 6; ++t) {
        bool dup = false;
        for (int u = 0; u < t; ++u)
            if (P[u][0] == P[t][0] && P[u][1] == P[t][1] && P[u][2] == P[t][2]) dup = true;
        if (dup) continue;
        const float* src = U + ((((L * 16 + P[t][0]) * 16 + P[t][1]) * 16 + P[t][2]) * 30);
#pragma unroll
        for (int p = 0; p < 30; ++p) s[p] += src[p];
    }
    float* dst = usym3 + (size_t)(Lout * NQ3 + q) * 32;
#pragma unroll
    for (int p = 0; p < 30; ++p) dst[p] = s[p];
    dst[30] = 0.f; dst[31] = 0.f;
}

// ---- build symmetrized quadratic U: usym2[Lout][q2][16] (p padded to 16) ----
__global__ void k_usym2(const float* __restrict__ U2_0, const float* __restrict__ U2_1,
                        float* __restrict__ usym2) {
    int tid = blockIdx.x * 256 + threadIdx.x;
    if (tid >= 4 * 256) return;
    int Lout = tid >> 8;
    int r = tid & 255;
    int a = r >> 4, b = r & 15;
    if (a > b) return;
    int q = d_OFF2[a] + (b - a);
    const float* U = (Lout == 0) ? U2_0 : U2_1;
    int L = (Lout == 0) ? 0 : (Lout - 1);
    float* dst = usym2 + (size_t)(Lout * NQ2 + q) * 16;
#pragma unroll
    for (int p = 0; p < 12; ++p) {
        float v = U[((L * 16 + a) * 16 + b) * 12 + p];
        if (a != b) v += U[((L * 16 + b) * 16 + a) * 12 + p];
        dst[p] = v;
    }
    dst[12] = 0.f; dst[13] = 0.f; dst[14] = 0.f; dst[15] = 0.f;
}

// ---- per-species node lists ----
__global__ void k_plist(const int* __restrict__ species, int* __restrict__ nodelist,
                        int* __restrict__ counts) {
    __shared__ int cnt[NELEM];
    int t = threadIdx.x;
    if (t < NELEM) cnt[t] = 0;
    __syncthreads();
    int e = species[t];
    int pos = atomicAdd(&cnt[e], 1);
    nodelist[e * NN + pos] = t;
    __syncthreads();
    if (t < NELEM) counts[t] = cnt[t];
}

// ---- fold species weights: call4[(e*128+c)*968 + q] = {coef_L0..L3} ----
__global__ __launch_bounds__(256) void k_fold(
    const float* __restrict__ usym3, const float* __restrict__ usym2,
    const float* __restrict__ U1_0, const float* __restrict__ U1_1,
    const float* __restrict__ W1_0, const float* __restrict__ W2_0, const float* __restrict__ W3_0,
    const float* __restrict__ W1_1, const float* __restrict__ W2_1, const float* __restrict__ W3_1,
    float4* __restrict__ call4) {
    int e = blockIdx.x >> 7;
    int c = blockIdx.x & 127;
    __shared__ __align__(16) float w3s[2][32];
    __shared__ __align__(16) float w2s[2][16];
    __shared__ float w1s[2][4];
    int t = threadIdx.x;
    if (t < 32)            w3s[0][t]      = (t < 30)      ? W3_0[(e * 30 + t) * CC + c] : 0.f;
    else if (t < 64)       w3s[1][t - 32] = (t - 32 < 30) ? W3_1[(e * 30 + (t - 32)) * CC + c] : 0.f;
    else if (t < 80)       w2s[0][t - 64] = (t - 64 < 12) ? W2_0[(e * 12 + (t - 64)) * CC + c] : 0.f;
    else if (t < 96)       w2s[1][t - 80] = (t - 80 < 12) ? W2_1[(e * 12 + (t - 80)) * CC + c] : 0.f;
    else if (t < 100)      w1s[0][t - 96]  = W1_0[(e * 4 + (t - 96)) * CC + c];
    else if (t < 104)      w1s[1][t - 100] = W1_1[(e * 4 + (t - 100)) * CC + c];
    __syncthreads();
    size_t base = (size_t)blockIdx.x * NQ;
    for (int q = t; q < NQ; q += 256) {
        float r[4];
        if (q < NQ3) {
#pragma unroll
            for (int L = 0; L < 4; ++L) {
                const float4* up = (const float4*)(usym3 + (size_t)(L * NQ3 + q) * 32);
                const float4* w4 = (const float4*)((L == 0) ? w3s[0] : w3s[1]);
                float acc = 0.f;
#pragma unroll
                for (int p4 = 0; p4 < 8; ++p4) {
                    float4 u = up[p4], w = w4[p4];
                    acc += u.x * w.x + u.y * w.y + u.z * w.z + u.w * w.w;
                }
                r[L] = acc;
            }
        } else if (q < NQ3 + NQ2) {
            int q2 = q - NQ3;
#pragma unroll
            for (int L = 0; L < 4; ++L) {
                const float4* up = (const float4*)(usym2 + (size_t)(L * NQ2 + q2) * 16);
                const float4* w4 = (const float4*)((L == 0) ? w2s[0] : w2s[1]);
                float acc = 0.f;
#pragma unroll
                for (int p4 = 0; p4 < 4; ++p4) {
                    float4 u = up[p4], w = w4[p4];
                    acc += u.x * w.x + u.y * w.y + u.z * w.z + u.w * w.w;
                }
                r[L] = acc;
            }
        } else {
            int i = q - (NQ3 + NQ2);
            {
                float4 u = ((const float4*)U1_0)[i];
                r[0] = u.x * w1s[0][0] + u.y * w1s[0][1] + u.z * w1s[0][2] + u.w * w1s[0][3];
            }
#pragma unroll
            for (int L = 1; L < 4; ++L) {
                float4 u = ((const float4*)U1_1)[(L - 1) * 16 + i];
                r[L] = u.x * w1s[1][0] + u.y * w1s[1][1] + u.z * w1s[1][2] + u.w * w1s[1][3];
            }
        }
        call4[base + q] = make_float4(r[0], r[1], r[2], r[3]);
    }
}

// ---- polynomial eval: one wave per (e,c,half); one thread per node ----
__global__ __launch_bounds__(64) void k_eval(
    const float* __restrict__ x, const int* __restrict__ nodelist,
    const int* __restrict__ counts, const float4* __restrict__ call4,
    float4* __restrict__ fout) {
    int b = blockIdx.x;          // ((e*128 + c) << 1) | half
    int half = b & 1;
    int ec = b >> 1;
    int e = ec >> 7;
    int c = ec & 127;
    int cnt = counts[e];
    const float4* cf = call4 + (size_t)ec * NQ;
    for (int idx = half * 64 + (int)threadIdx.x; idx < cnt; idx += 128) {
        int n = nodelist[e * NN + idx];
        const float4* xp = (const float4*)(x + ((size_t)n * CC + c) * 16);
        float4 t0 = xp[0], t1 = xp[1], t2 = xp[2], t3 = xp[3];
        float xv[16] = {t0.x, t0.y, t0.z, t0.w, t1.x, t1.y, t1.z, t1.w,
                        t2.x, t2.y, t2.z, t2.w, t3.x, t3.y, t3.z, t3.w};
        float a0 = 0.f, a1 = 0.f, a2 = 0.f, a3 = 0.f;
        int q = 0;
        // cubic monomials (sorted triples, lexicographic == coeff order)
#pragma unroll
        for (int a = 0; a < 16; ++a) {
#pragma unroll
            for (int bb = a; bb < 16; ++bb) {
                float pab = xv[a] * xv[bb];
#pragma unroll
                for (int cc2 = bb; cc2 < 16; ++cc2) {
                    float4 w = cf[q];
                    float m = pab * xv[cc2];
                    a0 = fmaf(m, w.x, a0); a1 = fmaf(m, w.y, a1);
                    a2 = fmaf(m, w.z, a2); a3 = fmaf(m, w.w, a3);
                    ++q;
                }
            }
        }
        // quadratic monomials
#pragma unroll
        for (int a = 0; a < 16; ++a) {
#pragma unroll
            for (int bb = a; bb < 16; ++bb) {
                float4 w = cf[q];
                float m = xv[a] * xv[bb];
                a0 = fmaf(m, w.x, a0); a1 = fmaf(m, w.y, a1);
                a2 = fmaf(m, w.z, a2); a3 = fmaf(m, w.w, a3);
                ++q;
            }
        }
        // linear
#pragma unroll
        for (int a = 0; a < 16; ++a) {
            float4 w = cf[q];
            float m = xv[a];
            a0 = fmaf(m, w.x, a0); a1 = fmaf(m, w.y, a1);
            a2 = fmaf(m, w.z, a2); a3 = fmaf(m, w.w, a3);
            ++q;
        }
        fout[(size_t)n * CC + c] = make_float4(a0, a1, a2, a3);
    }
}

// ---- epilogue: y0 = f0 @ Wlin0 * s ; y1 = f1 @ Wlin1 * s (per xyz) ----
__global__ __launch_bounds__(256) void k_linear(
    const float4* __restrict__ fin, const float* __restrict__ Wlin0,
    const float* __restrict__ Wlin1, float* __restrict__ out) {
    __shared__ float4 fl[256];
    int t = threadIdx.x;
    fl[t] = fin[(size_t)blockIdx.x * 256 + t];
    __syncthreads();
    int nl = t >> 7, k = t & 127;
    int n = blockIdx.x * 2 + nl;
    float a0 = 0.f, a1 = 0.f, a2 = 0.f, a3 = 0.f;
#pragma unroll 8
    for (int c = 0; c < CC; ++c) {
        float4 f = fl[nl * CC + c];
        float w0 = Wlin0[c * CC + k];
        float w1 = Wlin1[c * CC + k];
        a0 = fmaf(f.x, w0, a0);
        a1 = fmaf(f.y, w1, a1);
        a2 = fmaf(f.z, w1, a2);
        a3 = fmaf(f.w, w1, a3);
    }
    const float s = 0.08838834764831845f; // 1/sqrt(128)
    float* o = out + (size_t)n * 512;
    o[k] = a0 * s;
    o[128 + 3 * k + 0] = a1 * s;
    o[128 + 3 * k + 1] = a2 * s;
    o[128 + 3 * k + 2] = a3 * s;
}

extern "C" void kernel_launch(void* const* d_in, const int* in_sizes, int n_in,
                              void* d_out, int out_size, void* d_ws, size_t ws_size,
                              hipStream_t stream) {
    const float* x     = (const float*)d_in[0];
    const int*   spec  = (const int*)d_in[1];
    const float* U1_0  = (const float*)d_in[2];
    const float* U2_0  = (const float*)d_in[3];
    const float* U3_0  = (const float*)d_in[4];
    const float* W1_0  = (const float*)d_in[5];
    const float* W2_0  = (const float*)d_in[6];
    const float* W3_0  = (const float*)d_in[7];
    const float* Wl_0  = (const float*)d_in[8];
    const float* U1_1  = (const float*)d_in[9];
    const float* U2_1  = (const float*)d_in[10];
    const float* U3_1  = (const float*)d_in[11];
    const float* W1_1  = (const float*)d_in[12];
    const float* W2_1  = (const float*)d_in[13];
    const float* W3_1  = (const float*)d_in[14];
    const float* Wl_1  = (const float*)d_in[15];

    char* ws = (char*)d_ws;
    float*  usym3    = (float*)(ws + USYM3_OFF);
    float*  usym2    = (float*)(ws + USYM2_OFF);
    int*    nodelist = (int*)(ws + NL_OFF);
    int*    counts   = (int*)(ws + CNT_OFF);
    float4* call4    = (float4*)(ws + CALL_OFF);
    float4* fbuf     = (float4*)(ws + F_OFF);

    k_usym3<<<dim3(64), dim3(256), 0, stream>>>(U3_0, U3_1, usym3);
    k_usym2<<<dim3(4), dim3(256), 0, stream>>>(U2_0, U2_1, usym2);
    k_plist<<<dim3(1), dim3(1024), 0, stream>>>(spec, nodelist, counts);
    k_fold<<<dim3(1280), dim3(256), 0, stream>>>(usym3, usym2, U1_0, U1_1,
                                                 W1_0, W2_0, W3_0, W1_1, W2_1, W3_1, call4);
    k_eval<<<dim3(2560), dim3(64), 0, stream>>>(x, nodelist, counts, call4, fbuf);
    k_linear<<<dim3(512), dim3(256), 0, stream>>>(fbuf, Wl_0, Wl_1, (float*)d_out);
}

// Round 2
// 191.423 us; speedup vs baseline: 1.8677x; 1.8677x over previous
//
#include <hip/hip_runtime.h>

// ---------------- problem constants ----------------
#define NN    1024   // nodes
#define CC    128    // channels
#define NELEM 10
#define NQ3   816    // C(18,3) sorted triples over 16
#define NQ2   136    // sorted pairs
#define NQ    968    // 816 + 136 + 16

// ---------------- workspace layout (bytes) ----------------
#define USYM3_OFF 0          // float[4][816][32]  = 417792
#define USYM2_OFF 417792     // float[4][136][16]  = 34816  -> 452608
#define NL_OFF    452608     // int[10][1024]      = 40960  -> 493568
#define CNT_OFF   493568     // int[10]
#define CALL_OFF  524288     // float4[1280][968]  = 19824640 -> 20348928
#define F_OFF     20447232   // float4[1024][128]  = 2097152  -> 22544384

__device__ __constant__ int d_OFF2[16] = {0,16,31,45,58,70,81,91,100,108,115,121,126,130,133,135};
__device__ __constant__ int d_OFF3[16] = {0,136,256,361,452,530,596,651,696,732,760,781,796,806,812,815};

// ---- build symmetrized cubic U:  usym3[Lout][q3][32] (p padded to 32) ----
__global__ void k_usym3(const float* __restrict__ U3_0, const float* __restrict__ U3_1,
                        float* __restrict__ usym3) {
    int tid = blockIdx.x * 256 + threadIdx.x;
    if (tid >= 4 * 4096) return;
    int Lout = tid >> 12;
    int r = tid & 4095;
    int a = r >> 8, b = (r >> 4) & 15, m = r & 15;
    if (a > b || b > m) return;                       // only sorted triples
    int q = d_OFF3[a] + (d_OFF2[b] - d_OFF2[a]) + (m - b);
    const float* U = (Lout == 0) ? U3_0 : U3_1;
    int L = (Lout == 0) ? 0 : (Lout - 1);
    int P[6][3] = {{a,b,m},{a,m,b},{b,a,m},{b,m,a},{m,a,b},{m,b,a}};
    float s[30];
#pragma unroll
    for (int p = 0; p < 30; ++p) s[p] = 0.f;
    for (int t = 0; t < 6; ++t) {
        bool dup = false;
        for (int u = 0; u < t; ++u)
            if (P[u][0] == P[t][0] && P[u][1] == P[t][1] && P[u][2] == P[t][2]) dup = true;
        if (dup) continue;
        const float* src = U + ((((L * 16 + P[t][0]) * 16 + P[t][1]) * 16 + P[t][2]) * 30);
#pragma unroll
        for (int p = 0; p < 30; ++p) s[p] += src[p];
    }
    float* dst = usym3 + (size_t)(Lout * NQ3 + q) * 32;
#pragma unroll
    for (int p = 0; p < 30; ++p) dst[p] = s[p];
    dst[30] = 0.f; dst[31] = 0.f;
}

// ---- build symmetrized quadratic U: usym2[Lout][q2][16] (p padded to 16) ----
__global__ void k_usym2(const float* __restrict__ U2_0, const float* __restrict__ U2_1,
                        float* __restrict__ usym2) {
    int tid = blockIdx.x * 256 + threadIdx.x;
    if (tid >= 4 * 256) return;
    int Lout = tid >> 8;
    int r = tid & 255;
    int a = r >> 4, b = r & 15;
    if (a > b) return;
    int q = d_OFF2[a] + (b - a);
    const float* U = (Lout == 0) ? U2_0 : U2_1;
    int L = (Lout == 0) ? 0 : (Lout - 1);
    float* dst = usym2 + (size_t)(Lout * NQ2 + q) * 16;
#pragma unroll
    for (int p = 0; p < 12; ++p) {
        float v = U[((L * 16 + a) * 16 + b) * 12 + p];
        if (a != b) v += U[((L * 16 + b) * 16 + a) * 12 + p];
        dst[p] = v;
    }
    dst[12] = 0.f; dst[13] = 0.f; dst[14] = 0.f; dst[15] = 0.f;
}

// ---- per-species node lists ----
__global__ void k_plist(const int* __restrict__ species, int* __restrict__ nodelist,
                        int* __restrict__ counts) {
    __shared__ int cnt[NELEM];
    int t = threadIdx.x;
    if (t < NELEM) cnt[t] = 0;
    __syncthreads();
    int e = species[t];
    int pos = atomicAdd(&cnt[e], 1);
    nodelist[e * NN + pos] = t;
    __syncthreads();
    if (t < NELEM) counts[t] = cnt[t];
}

// ---- fold species weights: call4[(e*128+c)*968 + q] = {coef_L0..L3} ----
__global__ __launch_bounds__(256) void k_fold(
    const float* __restrict__ usym3, const float* __restrict__ usym2,
    const float* __restrict__ U1_0, const float* __restrict__ U1_1,
    const float* __restrict__ W1_0, const float* __restrict__ W2_0, const float* __restrict__ W3_0,
    const float* __restrict__ W1_1, const float* __restrict__ W2_1, const float* __restrict__ W3_1,
    float4* __restrict__ call4) {
    int e = blockIdx.x >> 7;
    int c = blockIdx.x & 127;
    __shared__ __align__(16) float w3s[2][32];
    __shared__ __align__(16) float w2s[2][16];
    __shared__ float w1s[2][4];
    int t = threadIdx.x;
    if (t < 32)            w3s[0][t]      = (t < 30)      ? W3_0[(e * 30 + t) * CC + c] : 0.f;
    else if (t < 64)       w3s[1][t - 32] = (t - 32 < 30) ? W3_1[(e * 30 + (t - 32)) * CC + c] : 0.f;
    else if (t < 80)       w2s[0][t - 64] = (t - 64 < 12) ? W2_0[(e * 12 + (t - 64)) * CC + c] : 0.f;
    else if (t < 96)       w2s[1][t - 80] = (t - 80 < 12) ? W2_1[(e * 12 + (t - 80)) * CC + c] : 0.f;
    else if (t < 100)      w1s[0][t - 96]  = W1_0[(e * 4 + (t - 96)) * CC + c];
    else if (t < 104)      w1s[1][t - 100] = W1_1[(e * 4 + (t - 100)) * CC + c];
    __syncthreads();
    size_t base = (size_t)blockIdx.x * NQ;
    for (int q = t; q < NQ; q += 256) {
        float r[4];
        if (q < NQ3) {
#pragma unroll
            for (int L = 0; L < 4; ++L) {
                const float4* up = (const float4*)(usym3 + (size_t)(L * NQ3 + q) * 32);
                const float4* w4 = (const float4*)((L == 0) ? w3s[0] : w3s[1]);
                float acc = 0.f;
#pragma unroll
                for (int p4 = 0; p4 < 8; ++p4) {
                    float4 u = up[p4], w = w4[p4];
                    acc += u.x * w.x + u.y * w.y + u.z * w.z + u.w * w.w;
                }
                r[L] = acc;
            }
        } else if (q < NQ3 + NQ2) {
            int q2 = q - NQ3;
#pragma unroll
            for (int L = 0; L < 4; ++L) {
                const float4* up = (const float4*)(usym2 + (size_t)(L * NQ2 + q2) * 16);
                const float4* w4 = (const float4*)((L == 0) ? w2s[0] : w2s[1]);
                float acc = 0.f;
#pragma unroll
                for (int p4 = 0; p4 < 4; ++p4) {
                    float4 u = up[p4], w = w4[p4];
                    acc += u.x * w.x + u.y * w.y + u.z * w.z + u.w * w.w;
                }
                r[L] = acc;
            }
        } else {
            int i = q - (NQ3 + NQ2);
            {
                float4 u = ((const float4*)U1_0)[i];
                r[0] = u.x * w1s[0][0] + u.y * w1s[0][1] + u.z * w1s[0][2] + u.w * w1s[0][3];
            }
#pragma unroll
            for (int L = 1; L < 4; ++L) {
                float4 u = ((const float4*)U1_1)[(L - 1) * 16 + i];
                r[L] = u.x * w1s[1][0] + u.y * w1s[1][1] + u.z * w1s[1][2] + u.w * w1s[1][3];
            }
        }
        call4[base + q] = make_float4(r[0], r[1], r[2], r[3]);
    }
}

// ---- polynomial eval: block = one (e,c); coeffs staged in LDS (broadcast reads);
// ---- 4 waves = node-slots 0..127 x q-half {a<4 | a>=4} ----
__global__ __launch_bounds__(256) void k_eval(
    const float* __restrict__ x, const int* __restrict__ nodelist,
    const int* __restrict__ counts, const float4* __restrict__ call4,
    float4* __restrict__ fout) {
    __shared__ __align__(16) float4 cf_lds[NQ];     // 15488 B
    __shared__ __align__(16) float4 part[2][128];   // 4096 B
    int ec = blockIdx.x;
    int e = ec >> 7;
    int cnt = counts[e];
    const float4* cf = call4 + (size_t)ec * NQ;
    int t = threadIdx.x;
    // stage coefficients (coalesced)
    for (int i = t; i < NQ; i += 256) cf_lds[i] = cf[i];
    __syncthreads();
    if (cnt == 0) return;
    int slot = t & 127;
    int qh = t >> 7;

    for (int sb = 0; sb < cnt; sb += 128) {
        int idx = sb + slot;
        bool valid = idx < cnt;
        int n = valid ? nodelist[e * NN + idx] : 0;
        float xv[16];
        if (valid) {
            const float4* xp = (const float4*)(x + ((size_t)n * CC + (ec & 127)) * 16);
            float4 t0 = xp[0], t1 = xp[1], t2 = xp[2], t3 = xp[3];
            xv[0]=t0.x; xv[1]=t0.y; xv[2]=t0.z; xv[3]=t0.w;
            xv[4]=t1.x; xv[5]=t1.y; xv[6]=t1.z; xv[7]=t1.w;
            xv[8]=t2.x; xv[9]=t2.y; xv[10]=t2.z; xv[11]=t2.w;
            xv[12]=t3.x; xv[13]=t3.y; xv[14]=t3.z; xv[15]=t3.w;
        } else {
#pragma unroll
            for (int i = 0; i < 16; ++i) xv[i] = 0.f;
        }
        float a0 = 0.f, a1 = 0.f, a2 = 0.f, a3 = 0.f;
        if (qh == 0) {
            // cubic monomials with a in [0,4): q = 0..451
            int q = 0;
#pragma unroll
            for (int a = 0; a < 4; ++a) {
#pragma unroll
                for (int b = a; b < 16; ++b) {
                    float pab = xv[a] * xv[b];
#pragma unroll
                    for (int m = b; m < 16; ++m) {
                        float4 w = cf_lds[q];
                        float mo = pab * xv[m];
                        a0 = fmaf(mo, w.x, a0); a1 = fmaf(mo, w.y, a1);
                        a2 = fmaf(mo, w.z, a2); a3 = fmaf(mo, w.w, a3);
                        ++q;
                    }
                }
            }
            // quadratic monomials with a in [0,4): q = NQ3 + 0..57
            q = NQ3;
#pragma unroll
            for (int a = 0; a < 4; ++a) {
#pragma unroll
                for (int b = a; b < 16; ++b) {
                    float4 w = cf_lds[q];
                    float mo = xv[a] * xv[b];
                    a0 = fmaf(mo, w.x, a0); a1 = fmaf(mo, w.y, a1);
                    a2 = fmaf(mo, w.z, a2); a3 = fmaf(mo, w.w, a3);
                    ++q;
                }
            }
        } else {
            // cubic monomials with a in [4,16): q = 452..815
            int q = 452;
#pragma unroll
            for (int a = 4; a < 16; ++a) {
#pragma unroll
                for (int b = a; b < 16; ++b) {
                    float pab = xv[a] * xv[b];
#pragma unroll
                    for (int m = b; m < 16; ++m) {
                        float4 w = cf_lds[q];
                        float mo = pab * xv[m];
                        a0 = fmaf(mo, w.x, a0); a1 = fmaf(mo, w.y, a1);
                        a2 = fmaf(mo, w.z, a2); a3 = fmaf(mo, w.w, a3);
                        ++q;
                    }
                }
            }
            // quadratic monomials with a in [4,16): q = NQ3 + 58..135
            q = NQ3 + 58;
#pragma unroll
            for (int a = 4; a < 16; ++a) {
#pragma unroll
                for (int b = a; b < 16; ++b) {
                    float4 w = cf_lds[q];
                    float mo = xv[a] * xv[b];
                    a0 = fmaf(mo, w.x, a0); a1 = fmaf(mo, w.y, a1);
                    a2 = fmaf(mo, w.z, a2); a3 = fmaf(mo, w.w, a3);
                    ++q;
                }
            }
            // linear: q = NQ3 + NQ2 .. NQ
            q = NQ3 + NQ2;
#pragma unroll
            for (int a = 0; a < 16; ++a) {
                float4 w = cf_lds[q];
                float mo = xv[a];
                a0 = fmaf(mo, w.x, a0); a1 = fmaf(mo, w.y, a1);
                a2 = fmaf(mo, w.z, a2); a3 = fmaf(mo, w.w, a3);
                ++q;
            }
        }
        part[qh][slot] = make_float4(a0, a1, a2, a3);
        __syncthreads();
        if (t < 128 && valid) {
            float4 pa = part[0][slot], pb = part[1][slot];
            fout[(size_t)n * CC + (ec & 127)] =
                make_float4(pa.x + pb.x, pa.y + pb.y, pa.z + pb.z, pa.w + pb.w);
        }
        __syncthreads();
    }
}

// ---- epilogue: y0 = f0 @ Wlin0 * s ; y1 = f1 @ Wlin1 * s (per xyz) ----
__global__ __launch_bounds__(256) void k_linear(
    const float4* __restrict__ fin, const float* __restrict__ Wlin0,
    const float* __restrict__ Wlin1, float* __restrict__ out) {
    __shared__ float4 fl[256];
    int t = threadIdx.x;
    fl[t] = fin[(size_t)blockIdx.x * 256 + t];
    __syncthreads();
    int nl = t >> 7, k = t & 127;
    int n = blockIdx.x * 2 + nl;
    float a0 = 0.f, a1 = 0.f, a2 = 0.f, a3 = 0.f;
#pragma unroll 8
    for (int c = 0; c < CC; ++c) {
        float4 f = fl[nl * CC + c];
        float w0 = Wlin0[c * CC + k];
        float w1 = Wlin1[c * CC + k];
        a0 = fmaf(f.x, w0, a0);
        a1 = fmaf(f.y, w1, a1);
        a2 = fmaf(f.z, w1, a2);
        a3 = fmaf(f.w, w1, a3);
    }
    const float s = 0.08838834764831845f; // 1/sqrt(128)
    float* o = out + (size_t)n * 512;
    o[k] = a0 * s;
    o[128 + 3 * k + 0] = a1 * s;
    o[128 + 3 * k + 1] = a2 * s;
    o[128 + 3 * k + 2] = a3 * s;
}

extern "C" void kernel_launch(void* const* d_in, const int* in_sizes, int n_in,
                              void* d_out, int out_size, void* d_ws, size_t ws_size,
                              hipStream_t stream) {
    const float* x     = (const float*)d_in[0];
    const int*   spec  = (const int*)d_in[1];
    const float* U1_0  = (const float*)d_in[2];
    const float* U2_0  = (const float*)d_in[3];
    const float* U3_0  = (const float*)d_in[4];
    const float* W1_0  = (const float*)d_in[5];
    const float* W2_0  = (const float*)d_in[6];
    const float* W3_0  = (const float*)d_in[7];
    const float* Wl_0  = (const float*)d_in[8];
    const float* U1_1  = (const float*)d_in[9];
    const float* U2_1  = (const float*)d_in[10];
    const float* U3_1  = (const float*)d_in[11];
    const float* W1_1  = (const float*)d_in[12];
    const float* W2_1  = (const float*)d_in[13];
    const float* W3_1  = (const float*)d_in[14];
    const float* Wl_1  = (const float*)d_in[15];

    char* ws = (char*)d_ws;
    float*  usym3    = (float*)(ws + USYM3_OFF);
    float*  usym2    = (float*)(ws + USYM2_OFF);
    int*    nodelist = (int*)(ws + NL_OFF);
    int*    counts   = (int*)(ws + CNT_OFF);
    float4* call4    = (float4*)(ws + CALL_OFF);
    float4* fbuf     = (float4*)(ws + F_OFF);

    k_usym3<<<dim3(64), dim3(256), 0, stream>>>(U3_0, U3_1, usym3);
    k_usym2<<<dim3(4), dim3(256), 0, stream>>>(U2_0, U2_1, usym2);
    k_plist<<<dim3(1), dim3(1024), 0, stream>>>(spec, nodelist, counts);
    k_fold<<<dim3(1280), dim3(256), 0, stream>>>(usym3, usym2, U1_0, U1_1,
                                                 W1_0, W2_0, W3_0, W1_1, W2_1, W3_1, call4);
    k_eval<<<dim3(1280), dim3(256), 0, stream>>>(x, nodelist, counts, call4, fbuf);
    k_linear<<<dim3(512), dim3(256), 0, stream>>>(fbuf, Wl_0, Wl_1, (float*)d_out);
}

// Round 3
// 170.870 us; speedup vs baseline: 2.0924x; 1.1203x over previous
//
#include <hip/hip_runtime.h>

typedef float v2f __attribute__((ext_vector_type(2)));

// ---------------- problem constants ----------------
#define NN    1024
#define CC    128
#define NELEM 10
#define NQ3   816
#define NQ2   136
#define NQ    968

// ---------------- workspace layout (bytes) ----------------
#define USYM3_OFF 0          // float[4][816][32]
#define USYM2_OFF 417792     // float[4][136][16]
#define NL_OFF    452608     // int[10][1024]
#define CNT_OFF   493568     // int[10]
#define CALL_OFF  524288     // float4[1280][968]
#define F_OFF     20447232   // float4[1024][128]

__device__ __constant__ int d_OFF2[16] = {0,16,31,45,58,70,81,91,100,108,115,121,126,130,133,135};
__device__ __constant__ int d_OFF3[16] = {0,136,256,361,452,530,596,651,696,732,760,781,796,806,812,815};

// ---- build symmetrized cubic U ----
__global__ void k_usym3(const float* __restrict__ U3_0, const float* __restrict__ U3_1,
                        float* __restrict__ usym3) {
    int tid = blockIdx.x * 256 + threadIdx.x;
    if (tid >= 4 * 4096) return;
    int Lout = tid >> 12;
    int r = tid & 4095;
    int a = r >> 8, b = (r >> 4) & 15, m = r & 15;
    if (a > b || b > m) return;
    int q = d_OFF3[a] + (d_OFF2[b] - d_OFF2[a]) + (m - b);
    const float* U = (Lout == 0) ? U3_0 : U3_1;
    int L = (Lout == 0) ? 0 : (Lout - 1);
    int P[6][3] = {{a,b,m},{a,m,b},{b,a,m},{b,m,a},{m,a,b},{m,b,a}};
    float s[30];
#pragma unroll
    for (int p = 0; p < 30; ++p) s[p] = 0.f;
    for (int t = 0; t < 6; ++t) {
        bool dup = false;
        for (int u = 0; u < t; ++u)
            if (P[u][0] == P[t][0] && P[u][1] == P[t][1] && P[u][2] == P[t][2]) dup = true;
        if (dup) continue;
        const float* src = U + ((((L * 16 + P[t][0]) * 16 + P[t][1]) * 16 + P[t][2]) * 30);
#pragma unroll
        for (int p = 0; p < 30; ++p) s[p] += src[p];
    }
    float* dst = usym3 + (size_t)(Lout * NQ3 + q) * 32;
#pragma unroll
    for (int p = 0; p < 30; ++p) dst[p] = s[p];
    dst[30] = 0.f; dst[31] = 0.f;
}

// ---- build symmetrized quadratic U ----
__global__ void k_usym2(const float* __restrict__ U2_0, const float* __restrict__ U2_1,
                        float* __restrict__ usym2) {
    int tid = blockIdx.x * 256 + threadIdx.x;
    if (tid >= 4 * 256) return;
    int Lout = tid >> 8;
    int r = tid & 255;
    int a = r >> 4, b = r & 15;
    if (a > b) return;
    int q = d_OFF2[a] + (b - a);
    const float* U = (Lout == 0) ? U2_0 : U2_1;
    int L = (Lout == 0) ? 0 : (Lout - 1);
    float* dst = usym2 + (size_t)(Lout * NQ2 + q) * 16;
#pragma unroll
    for (int p = 0; p < 12; ++p) {
        float v = U[((L * 16 + a) * 16 + b) * 12 + p];
        if (a != b) v += U[((L * 16 + b) * 16 + a) * 12 + p];
        dst[p] = v;
    }
    dst[12] = 0.f; dst[13] = 0.f; dst[14] = 0.f; dst[15] = 0.f;
}

// ---- per-species node lists ----
__global__ void k_plist(const int* __restrict__ species, int* __restrict__ nodelist,
                        int* __restrict__ counts) {
    __shared__ int cnt[NELEM];
    int t = threadIdx.x;
    if (t < NELEM) cnt[t] = 0;
    __syncthreads();
    int e = species[t];
    int pos = atomicAdd(&cnt[e], 1);
    nodelist[e * NN + pos] = t;
    __syncthreads();
    if (t < NELEM) counts[t] = cnt[t];
}

// ---- fold species weights: 4 channels per block (amortize usym reads) ----
__global__ __launch_bounds__(256) void k_fold(
    const float* __restrict__ usym3, const float* __restrict__ usym2,
    const float* __restrict__ U1_0, const float* __restrict__ U1_1,
    const float* __restrict__ W1_0, const float* __restrict__ W2_0, const float* __restrict__ W3_0,
    const float* __restrict__ W1_1, const float* __restrict__ W2_1, const float* __restrict__ W3_1,
    float4* __restrict__ call4) {
    int e  = blockIdx.x >> 5;
    int cq = blockIdx.x & 31;
    int t = threadIdx.x;
    int csub = t >> 6, lane = t & 63;
    int c = cq * 4 + csub;
    __shared__ __align__(16) float w3s[2][4][32];
    __shared__ __align__(16) float w2s[2][4][16];
    __shared__ float w1s[2][4][4];
    if (lane < 32)       w3s[0][csub][lane]      = (lane < 30)      ? W3_0[(e * 30 + lane) * CC + c] : 0.f;
    else                 w3s[1][csub][lane - 32] = (lane - 32 < 30) ? W3_1[(e * 30 + (lane - 32)) * CC + c] : 0.f;
    if (lane < 16)       w2s[0][csub][lane]      = (lane < 12)      ? W2_0[(e * 12 + lane) * CC + c] : 0.f;
    else if (lane < 32)  w2s[1][csub][lane - 16] = (lane - 16 < 12) ? W2_1[(e * 12 + (lane - 16)) * CC + c] : 0.f;
    else if (lane < 36)  w1s[0][csub][lane - 32] = W1_0[(e * 4 + (lane - 32)) * CC + c];
    else if (lane < 40)  w1s[1][csub][lane - 36] = W1_1[(e * 4 + (lane - 36)) * CC + c];
    __syncthreads();
    size_t base = ((size_t)e * CC + c) * NQ;
    for (int pass = 0; pass < 16; ++pass) {
        int q = pass * 64 + lane;
        if (q >= NQ) break;
        float r[4];
        if (q < NQ3) {
#pragma unroll
            for (int L = 0; L < 4; ++L) {
                const float4* up = (const float4*)(usym3 + (size_t)(L * NQ3 + q) * 32);
                const float4* w4 = (const float4*)((L == 0) ? w3s[0][csub] : w3s[1][csub]);
                float acc = 0.f;
#pragma unroll
                for (int p4 = 0; p4 < 8; ++p4) {
                    float4 u = up[p4], w = w4[p4];
                    acc += u.x * w.x + u.y * w.y + u.z * w.z + u.w * w.w;
                }
                r[L] = acc;
            }
        } else if (q < NQ3 + NQ2) {
            int q2 = q - NQ3;
#pragma unroll
            for (int L = 0; L < 4; ++L) {
                const float4* up = (const float4*)(usym2 + (size_t)(L * NQ2 + q2) * 16);
                const float4* w4 = (const float4*)((L == 0) ? w2s[0][csub] : w2s[1][csub]);
                float acc = 0.f;
#pragma unroll
                for (int p4 = 0; p4 < 4; ++p4) {
                    float4 u = up[p4], w = w4[p4];
                    acc += u.x * w.x + u.y * w.y + u.z * w.z + u.w * w.w;
                }
                r[L] = acc;
            }
        } else {
            int i = q - (NQ3 + NQ2);
            {
                float4 u = ((const float4*)U1_0)[i];
                r[0] = u.x * w1s[0][csub][0] + u.y * w1s[0][csub][1] + u.z * w1s[0][csub][2] + u.w * w1s[0][csub][3];
            }
#pragma unroll
            for (int L = 1; L < 4; ++L) {
                float4 u = ((const float4*)U1_1)[(L - 1) * 16 + i];
                r[L] = u.x * w1s[1][csub][0] + u.y * w1s[1][csub][1] + u.z * w1s[1][csub][2] + u.w * w1s[1][csub][3];
            }
        }
        call4[base + q] = make_float4(r[0], r[1], r[2], r[3]);
    }
}

// ---- monomial macros (q must be pre-set to the slice base; layout-lexicographic) ----
#define CUBIC(A0, A1) { \
    _Pragma("unroll") for (int a = (A0); a < (A1); ++a) { \
        _Pragma("unroll") for (int b = a; b < 16; ++b) { \
            v2f pab = xv[a] * xv[b]; \
            _Pragma("unroll") for (int m = b; m < 16; ++m) { \
                float4 w = cf_lds[q]; v2f mo = pab * xv[m]; \
                a0 += mo * w.x; a1 += mo * w.y; a2 += mo * w.z; a3 += mo * w.w; ++q; } } } }

#define QUAD(A0, A1) { \
    _Pragma("unroll") for (int a = (A0); a < (A1); ++a) { \
        _Pragma("unroll") for (int b = a; b < 16; ++b) { \
            float4 w = cf_lds[q]; v2f mo = xv[a] * xv[b]; \
            a0 += mo * w.x; a1 += mo * w.y; a2 += mo * w.z; a3 += mo * w.w; ++q; } } }

// ---- polynomial eval: block=(e,c); 4 wave-slices; 2 nodes/thread; pk-fp32 math ----
__global__ __launch_bounds__(256, 4) void k_eval(
    const float* __restrict__ x, const int* __restrict__ nodelist,
    const int* __restrict__ counts, const float4* __restrict__ call4,
    float4* __restrict__ fout) {
    __shared__ __align__(16) float4 cf_lds[NQ];      // 15488 B
    __shared__ __align__(16) v2f part[3][64][4];     // 6144 B
    int ec = blockIdx.x;
    int e = ec >> 7;
    int c = ec & 127;
    int cnt = counts[e];
    const float4* cf = call4 + (size_t)ec * NQ;
    int t = threadIdx.x;
    for (int i = t; i < NQ; i += 256) cf_lds[i] = cf[i];
    __syncthreads();
    int slice = t >> 6;
    int lane  = t & 63;

    for (int sb = 0; sb < cnt; sb += 128) {
        int i0 = sb + lane * 2, i1 = i0 + 1;
        bool v0i = i0 < cnt, v1i = i1 < cnt;
        int n0 = v0i ? nodelist[e * NN + i0] : 0;
        int n1 = v1i ? nodelist[e * NN + i1] : 0;
        const float4* xp0 = (const float4*)(x + ((size_t)n0 * CC + c) * 16);
        const float4* xp1 = (const float4*)(x + ((size_t)n1 * CC + c) * 16);
        float4 p0 = xp0[0], p1 = xp0[1], p2 = xp0[2], p3 = xp0[3];
        float4 q0 = xp1[0], q1 = xp1[1], q2 = xp1[2], q3 = xp1[3];
        v2f xv[16];
        xv[0]  = v2f{p0.x, q0.x}; xv[1]  = v2f{p0.y, q0.y};
        xv[2]  = v2f{p0.z, q0.z}; xv[3]  = v2f{p0.w, q0.w};
        xv[4]  = v2f{p1.x, q1.x}; xv[5]  = v2f{p1.y, q1.y};
        xv[6]  = v2f{p1.z, q1.z}; xv[7]  = v2f{p1.w, q1.w};
        xv[8]  = v2f{p2.x, q2.x}; xv[9]  = v2f{p2.y, q2.y};
        xv[10] = v2f{p2.z, q2.z}; xv[11] = v2f{p2.w, q2.w};
        xv[12] = v2f{p3.x, q3.x}; xv[13] = v2f{p3.y, q3.y};
        xv[14] = v2f{p3.z, q3.z}; xv[15] = v2f{p3.w, q3.w};
        if (!v0i) {
#pragma unroll
            for (int m = 0; m < 16; ++m) xv[m].x = 0.f;
        }
        if (!v1i) {
#pragma unroll
            for (int m = 0; m < 16; ++m) xv[m].y = 0.f;
        }
        v2f a0 = {0.f, 0.f}, a1 = {0.f, 0.f}, a2 = {0.f, 0.f}, a3 = {0.f, 0.f};
        int q;
        if (slice == 0) {            // cubic a=0..1 : q 0..255                (256)
            q = 0;   CUBIC(0, 2);
        } else if (slice == 1) {     // cubic a=2..3 + quad a=0..3             (254)
            q = 256; CUBIC(2, 4);
            q = NQ3; QUAD(0, 4);
        } else if (slice == 2) {     // cubic a=4..6 + quad a=4..9             (256)
            q = 452; CUBIC(4, 7);
            q = NQ3 + 58; QUAD(4, 10);
        } else {                     // cubic a=7..15 + quad a=10..15 + linear (202)
            q = 651; CUBIC(7, 16);
            q = NQ3 + 115; QUAD(10, 16);
            q = NQ3 + NQ2;
#pragma unroll
            for (int a = 0; a < 16; ++a) {
                float4 w = cf_lds[q]; v2f mo = xv[a];
                a0 += mo * w.x; a1 += mo * w.y; a2 += mo * w.z; a3 += mo * w.w; ++q;
            }
        }
        if (slice > 0) {
            part[slice - 1][lane][0] = a0; part[slice - 1][lane][1] = a1;
            part[slice - 1][lane][2] = a2; part[slice - 1][lane][3] = a3;
        }
        __syncthreads();
        if (slice == 0) {
            v2f s0 = a0 + part[0][lane][0] + part[1][lane][0] + part[2][lane][0];
            v2f s1 = a1 + part[0][lane][1] + part[1][lane][1] + part[2][lane][1];
            v2f s2 = a2 + part[0][lane][2] + part[1][lane][2] + part[2][lane][2];
            v2f s3 = a3 + part[0][lane][3] + part[1][lane][3] + part[2][lane][3];
            if (v0i) fout[(size_t)n0 * CC + c] = make_float4(s0.x, s1.x, s2.x, s3.x);
            if (v1i) fout[(size_t)n1 * CC + c] = make_float4(s0.y, s1.y, s2.y, s3.y);
        }
        __syncthreads();
    }
}

// ---- epilogue linear ----
__global__ __launch_bounds__(256) void k_linear(
    const float4* __restrict__ fin, const float* __restrict__ Wlin0,
    const float* __restrict__ Wlin1, float* __restrict__ out) {
    __shared__ float4 fl[256];
    int t = threadIdx.x;
    fl[t] = fin[(size_t)blockIdx.x * 256 + t];
    __syncthreads();
    int nl = t >> 7, k = t & 127;
    int n = blockIdx.x * 2 + nl;
    float a0 = 0.f, a1 = 0.f, a2 = 0.f, a3 = 0.f;
#pragma unroll 8
    for (int c = 0; c < CC; ++c) {
        float4 f = fl[nl * CC + c];
        float w0 = Wlin0[c * CC + k];
        float w1 = Wlin1[c * CC + k];
        a0 = fmaf(f.x, w0, a0);
        a1 = fmaf(f.y, w1, a1);
        a2 = fmaf(f.z, w1, a2);
        a3 = fmaf(f.w, w1, a3);
    }
    const float s = 0.08838834764831845f; // 1/sqrt(128)
    float* o = out + (size_t)n * 512;
    o[k] = a0 * s;
    o[128 + 3 * k + 0] = a1 * s;
    o[128 + 3 * k + 1] = a2 * s;
    o[128 + 3 * k + 2] = a3 * s;
}

extern "C" void kernel_launch(void* const* d_in, const int* in_sizes, int n_in,
                              void* d_out, int out_size, void* d_ws, size_t ws_size,
                              hipStream_t stream) {
    const float* x     = (const float*)d_in[0];
    const int*   spec  = (const int*)d_in[1];
    const float* U1_0  = (const float*)d_in[2];
    const float* U2_0  = (const float*)d_in[3];
    const float* U3_0  = (const float*)d_in[4];
    const float* W1_0  = (const float*)d_in[5];
    const float* W2_0  = (const float*)d_in[6];
    const float* W3_0  = (const float*)d_in[7];
    const float* Wl_0  = (const float*)d_in[8];
    const float* U1_1  = (const float*)d_in[9];
    const float* U2_1  = (const float*)d_in[10];
    const float* U3_1  = (const float*)d_in[11];
    const float* W1_1  = (const float*)d_in[12];
    const float* W2_1  = (const float*)d_in[13];
    const float* W3_1  = (const float*)d_in[14];
    const float* Wl_1  = (const float*)d_in[15];

    char* ws = (char*)d_ws;
    float*  usym3    = (float*)(ws + USYM3_OFF);
    float*  usym2    = (float*)(ws + USYM2_OFF);
    int*    nodelist = (int*)(ws + NL_OFF);
    int*    counts   = (int*)(ws + CNT_OFF);
    float4* call4    = (float4*)(ws + CALL_OFF);
    float4* fbuf     = (float4*)(ws + F_OFF);

    k_usym3<<<dim3(64), dim3(256), 0, stream>>>(U3_0, U3_1, usym3);
    k_usym2<<<dim3(4), dim3(256), 0, stream>>>(U2_0, U2_1, usym2);
    k_plist<<<dim3(1), dim3(1024), 0, stream>>>(spec, nodelist, counts);
    k_fold<<<dim3(320), dim3(256), 0, stream>>>(usym3, usym2, U1_0, U1_1,
                                                W1_0, W2_0, W3_0, W1_1, W2_1, W3_1, call4);
    k_eval<<<dim3(1280), dim3(256), 0, stream>>>(x, nodelist, counts, call4, fbuf);
    k_linear<<<dim3(512), dim3(256), 0, stream>>>(fbuf, Wl_0, Wl_1, (float*)d_out);
}

// Round 4
// 114.196 us; speedup vs baseline: 3.1308x; 1.4963x over previous
//
#include <hip/hip_runtime.h>

typedef float v2f __attribute__((ext_vector_type(2)));

// ---------------- problem constants ----------------
#define NN    1024
#define CC    128
#define NELEM 10
#define NQ3   816
#define NQ2   136
#define NQ    968
#define KP    48     // unified p-dim: 30 (w3) + 12 (w2) + 4 (w1) + 2 pad

// ---------------- workspace layout (bytes) ----------------
#define NL_OFF    0          // int[10][1024] = 40960
#define CNT_OFF   40960      // int[10]
#define CALL_OFF  524288     // float4[1280][968] = 19824640 -> 20348928
#define F_OFF     20447232   // float4[1024][128] = 2097152  -> 22544384
#define UHAT_OFF  20447232   // float[4][968][48] = 743424 (aliases F; dead before k_eval)

__device__ __constant__ int d_OFF2[16] = {0,16,31,45,58,70,81,91,100,108,115,121,126,130,133,135};
__device__ __constant__ int d_OFF3[16] = {0,136,256,361,452,530,596,651,696,732,760,781,796,806,812,815};

// ---- build symmetrized cubic rows of Uhat: q in [0,816), p[0..29] = sym3, rest 0 ----
__global__ void k_usym3(const float* __restrict__ U3_0, const float* __restrict__ U3_1,
                        float* __restrict__ uhat) {
    int tid = blockIdx.x * 256 + threadIdx.x;
    if (tid >= 4 * 4096) return;
    int Lout = tid >> 12;
    int r = tid & 4095;
    int a = r >> 8, b = (r >> 4) & 15, m = r & 15;
    if (a > b || b > m) return;
    int q = d_OFF3[a] + (d_OFF2[b] - d_OFF2[a]) + (m - b);
    const float* U = (Lout == 0) ? U3_0 : U3_1;
    int L = (Lout == 0) ? 0 : (Lout - 1);
    int P[6][3] = {{a,b,m},{a,m,b},{b,a,m},{b,m,a},{m,a,b},{m,b,a}};
    float s[30];
#pragma unroll
    for (int p = 0; p < 30; ++p) s[p] = 0.f;
    for (int t = 0; t < 6; ++t) {
        bool dup = false;
        for (int u = 0; u < t; ++u)
            if (P[u][0] == P[t][0] && P[u][1] == P[t][1] && P[u][2] == P[t][2]) dup = true;
        if (dup) continue;
        const float* src = U + ((((L * 16 + P[t][0]) * 16 + P[t][1]) * 16 + P[t][2]) * 30);
#pragma unroll
        for (int p = 0; p < 30; ++p) s[p] += src[p];
    }
    float* dst = uhat + ((size_t)Lout * NQ + q) * KP;
#pragma unroll
    for (int p = 0; p < 30; ++p) dst[p] = s[p];
#pragma unroll
    for (int p = 30; p < KP; ++p) dst[p] = 0.f;
}

// ---- quad rows (q in [816,952), p[30..41]) + linear rows (q in [952,968), p[42..45]) ----
__global__ void k_usym2lin(const float* __restrict__ U2_0, const float* __restrict__ U2_1,
                           const float* __restrict__ U1_0, const float* __restrict__ U1_1,
                           float* __restrict__ uhat) {
    int tid = blockIdx.x * 256 + threadIdx.x;
    if (tid < 1024) {
        int Lout = tid >> 8;
        int r = tid & 255;
        int a = r >> 4, b = r & 15;
        if (a > b) return;
        int q = NQ3 + d_OFF2[a] + (b - a);
        const float* U = (Lout == 0) ? U2_0 : U2_1;
        int L = (Lout == 0) ? 0 : (Lout - 1);
        float* dst = uhat + ((size_t)Lout * NQ + q) * KP;
#pragma unroll
        for (int p = 0; p < 30; ++p) dst[p] = 0.f;
#pragma unroll
        for (int p = 0; p < 12; ++p) {
            float v = U[((L * 16 + a) * 16 + b) * 12 + p];
            if (a != b) v += U[((L * 16 + b) * 16 + a) * 12 + p];
            dst[30 + p] = v;
        }
#pragma unroll
        for (int p = 42; p < KP; ++p) dst[p] = 0.f;
    } else if (tid < 1024 + 64) {
        int s2 = tid - 1024;
        int Lout = s2 >> 4, i = s2 & 15;
        int q = NQ3 + NQ2 + i;
        const float* U = (Lout == 0) ? U1_0 : U1_1;
        int L = (Lout == 0) ? 0 : (Lout - 1);
        float* dst = uhat + ((size_t)Lout * NQ + q) * KP;
#pragma unroll
        for (int p = 0; p < 42; ++p) dst[p] = 0.f;
#pragma unroll
        for (int p = 0; p < 4; ++p) dst[42 + p] = U[(L * 16 + i) * 4 + p];
        dst[46] = 0.f; dst[47] = 0.f;
    }
}

// ---- per-species node lists ----
__global__ void k_plist(const int* __restrict__ species, int* __restrict__ nodelist,
                        int* __restrict__ counts) {
    __shared__ int cnt[NELEM];
    int t = threadIdx.x;
    if (t < NELEM) cnt[t] = 0;
    __syncthreads();
    int e = species[t];
    int pos = atomicAdd(&cnt[e], 1);
    nodelist[e * NN + pos] = t;
    __syncthreads();
    if (t < NELEM) counts[t] = cnt[t];
}

// ---- fold: call4[ec][q].L = dot48(Uhat[L][q][:], Wcat[Lg][:]) ----
// block = (e, q-tile of 22); 256 thr = 128 c x 2 q-slots; U loads wave-uniform (L1 broadcast)
__global__ __launch_bounds__(256) void k_fold(
    const float* __restrict__ uhat,
    const float* __restrict__ W1_0, const float* __restrict__ W2_0, const float* __restrict__ W3_0,
    const float* __restrict__ W1_1, const float* __restrict__ W2_1, const float* __restrict__ W3_1,
    float4* __restrict__ call4) {
    int e  = blockIdx.x / 44;
    int qt = blockIdx.x % 44;
    int t = threadIdx.x;
    int c  = t & 127;
    int qs = t >> 7;
    float wr[2][KP];
#pragma unroll
    for (int p = 0; p < 30; ++p) {
        wr[0][p] = W3_0[(e * 30 + p) * CC + c];
        wr[1][p] = W3_1[(e * 30 + p) * CC + c];
    }
#pragma unroll
    for (int p = 0; p < 12; ++p) {
        wr[0][30 + p] = W2_0[(e * 12 + p) * CC + c];
        wr[1][30 + p] = W2_1[(e * 12 + p) * CC + c];
    }
#pragma unroll
    for (int p = 0; p < 4; ++p) {
        wr[0][42 + p] = W1_0[(e * 4 + p) * CC + c];
        wr[1][42 + p] = W1_1[(e * 4 + p) * CC + c];
    }
    wr[0][46] = wr[0][47] = wr[1][46] = wr[1][47] = 0.f;
    size_t base = ((size_t)e * CC + c) * NQ;
    for (int j = 0; j < 11; ++j) {
        int q = qt * 22 + qs * 11 + j;
        float r[4];
#pragma unroll
        for (int l = 0; l < 4; ++l) {
            const float4* up = (const float4*)(uhat + ((size_t)l * NQ + q) * KP);
            float acc0 = 0.f, acc1 = 0.f, acc2 = 0.f, acc3 = 0.f;
#pragma unroll
            for (int p4 = 0; p4 < 12; ++p4) {
                float4 u = up[p4];
                const float* w = (l == 0) ? wr[0] : wr[1];
                acc0 = fmaf(u.x, w[p4 * 4 + 0], acc0);
                acc1 = fmaf(u.y, w[p4 * 4 + 1], acc1);
                acc2 = fmaf(u.z, w[p4 * 4 + 2], acc2);
                acc3 = fmaf(u.w, w[p4 * 4 + 3], acc3);
            }
            r[l] = (acc0 + acc1) + (acc2 + acc3);
        }
        call4[base + q] = make_float4(r[0], r[1], r[2], r[3]);
    }
}

// ---- monomial macros (q pre-set to slice base; layout-lexicographic) ----
#define CUBIC(A0, A1) { \
    _Pragma("unroll") for (int a = (A0); a < (A1); ++a) { \
        _Pragma("unroll") for (int b = a; b < 16; ++b) { \
            v2f pab = xv[a] * xv[b]; \
            _Pragma("unroll") for (int m = b; m < 16; ++m) { \
                float4 w = cf_lds[q]; v2f mo = pab * xv[m]; \
                a0 += mo * w.x; a1 += mo * w.y; a2 += mo * w.z; a3 += mo * w.w; ++q; } } } }

#define QUAD(A0, A1) { \
    _Pragma("unroll") for (int a = (A0); a < (A1); ++a) { \
        _Pragma("unroll") for (int b = a; b < 16; ++b) { \
            float4 w = cf_lds[q]; v2f mo = xv[a] * xv[b]; \
            a0 += mo * w.x; a1 += mo * w.y; a2 += mo * w.z; a3 += mo * w.w; ++q; } } }

// ---- polynomial eval: block=(e,c); 4 wave-slices; 2 nodes/thread; pk-fp32 math ----
__global__ __launch_bounds__(256, 4) void k_eval(
    const float* __restrict__ x, const int* __restrict__ nodelist,
    const int* __restrict__ counts, const float4* __restrict__ call4,
    float4* __restrict__ fout) {
    __shared__ __align__(16) float4 cf_lds[NQ];      // 15488 B
    __shared__ __align__(16) v2f part[3][64][4];     // 6144 B
    int ec = blockIdx.x;
    int e = ec >> 7;
    int c = ec & 127;
    int cnt = counts[e];
    const float4* cf = call4 + (size_t)ec * NQ;
    int t = threadIdx.x;
    for (int i = t; i < NQ; i += 256) cf_lds[i] = cf[i];
    __syncthreads();
    int slice = t >> 6;
    int lane  = t & 63;

    for (int sb = 0; sb < cnt; sb += 128) {
        int i0 = sb + lane * 2, i1 = i0 + 1;
        bool v0i = i0 < cnt, v1i = i1 < cnt;
        int n0 = v0i ? nodelist[e * NN + i0] : 0;
        int n1 = v1i ? nodelist[e * NN + i1] : 0;
        const float4* xp0 = (const float4*)(x + ((size_t)n0 * CC + c) * 16);
        const float4* xp1 = (const float4*)(x + ((size_t)n1 * CC + c) * 16);
        float4 p0 = xp0[0], p1 = xp0[1], p2 = xp0[2], p3 = xp0[3];
        float4 q0 = xp1[0], q1 = xp1[1], q2 = xp1[2], q3 = xp1[3];
        v2f xv[16];
        xv[0]  = v2f{p0.x, q0.x}; xv[1]  = v2f{p0.y, q0.y};
        xv[2]  = v2f{p0.z, q0.z}; xv[3]  = v2f{p0.w, q0.w};
        xv[4]  = v2f{p1.x, q1.x}; xv[5]  = v2f{p1.y, q1.y};
        xv[6]  = v2f{p1.z, q1.z}; xv[7]  = v2f{p1.w, q1.w};
        xv[8]  = v2f{p2.x, q2.x}; xv[9]  = v2f{p2.y, q2.y};
        xv[10] = v2f{p2.z, q2.z}; xv[11] = v2f{p2.w, q2.w};
        xv[12] = v2f{p3.x, q3.x}; xv[13] = v2f{p3.y, q3.y};
        xv[14] = v2f{p3.z, q3.z}; xv[15] = v2f{p3.w, q3.w};
        if (!v0i) {
#pragma unroll
            for (int m = 0; m < 16; ++m) xv[m].x = 0.f;
        }
        if (!v1i) {
#pragma unroll
            for (int m = 0; m < 16; ++m) xv[m].y = 0.f;
        }
        v2f a0 = {0.f, 0.f}, a1 = {0.f, 0.f}, a2 = {0.f, 0.f}, a3 = {0.f, 0.f};
        int q;
        if (slice == 0) {            // cubic a=0..1 : q 0..255                (256)
            q = 0;   CUBIC(0, 2);
        } else if (slice == 1) {     // cubic a=2..3 + quad a=0..3             (254)
            q = 256; CUBIC(2, 4);
            q = NQ3; QUAD(0, 4);
        } else if (slice == 2) {     // cubic a=4..6 + quad a=4..9             (256)
            q = 452; CUBIC(4, 7);
            q = NQ3 + 58; QUAD(4, 10);
        } else {                     // cubic a=7..15 + quad a=10..15 + linear (202)
            q = 651; CUBIC(7, 16);
            q = NQ3 + 115; QUAD(10, 16);
            q = NQ3 + NQ2;
#pragma unroll
            for (int a = 0; a < 16; ++a) {
                float4 w = cf_lds[q]; v2f mo = xv[a];
                a0 += mo * w.x; a1 += mo * w.y; a2 += mo * w.z; a3 += mo * w.w; ++q;
            }
        }
        if (slice > 0) {
            part[slice - 1][lane][0] = a0; part[slice - 1][lane][1] = a1;
            part[slice - 1][lane][2] = a2; part[slice - 1][lane][3] = a3;
        }
        __syncthreads();
        if (slice == 0) {
            v2f s0 = a0 + part[0][lane][0] + part[1][lane][0] + part[2][lane][0];
            v2f s1 = a1 + part[0][lane][1] + part[1][lane][1] + part[2][lane][1];
            v2f s2 = a2 + part[0][lane][2] + part[1][lane][2] + part[2][lane][2];
            v2f s3 = a3 + part[0][lane][3] + part[1][lane][3] + part[2][lane][3];
            if (v0i) fout[(size_t)n0 * CC + c] = make_float4(s0.x, s1.x, s2.x, s3.x);
            if (v1i) fout[(size_t)n1 * CC + c] = make_float4(s0.y, s1.y, s2.y, s3.y);
        }
        __syncthreads();
    }
}

// ---- epilogue linear ----
__global__ __launch_bounds__(256) void k_linear(
    const float4* __restrict__ fin, const float* __restrict__ Wlin0,
    const float* __restrict__ Wlin1, float* __restrict__ out) {
    __shared__ float4 fl[256];
    int t = threadIdx.x;
    fl[t] = fin[(size_t)blockIdx.x * 256 + t];
    __syncthreads();
    int nl = t >> 7, k = t & 127;
    int n = blockIdx.x * 2 + nl;
    float a0 = 0.f, a1 = 0.f, a2 = 0.f, a3 = 0.f;
#pragma unroll 8
    for (int c = 0; c < CC; ++c) {
        float4 f = fl[nl * CC + c];
        float w0 = Wlin0[c * CC + k];
        float w1 = Wlin1[c * CC + k];
        a0 = fmaf(f.x, w0, a0);
        a1 = fmaf(f.y, w1, a1);
        a2 = fmaf(f.z, w1, a2);
        a3 = fmaf(f.w, w1, a3);
    }
    const float s = 0.08838834764831845f; // 1/sqrt(128)
    float* o = out + (size_t)n * 512;
    o[k] = a0 * s;
    o[128 + 3 * k + 0] = a1 * s;
    o[128 + 3 * k + 1] = a2 * s;
    o[128 + 3 * k + 2] = a3 * s;
}

extern "C" void kernel_launch(void* const* d_in, const int* in_sizes, int n_in,
                              void* d_out, int out_size, void* d_ws, size_t ws_size,
                              hipStream_t stream) {
    const float* x     = (const float*)d_in[0];
    const int*   spec  = (const int*)d_in[1];
    const float* U1_0  = (const float*)d_in[2];
    const float* U2_0  = (const float*)d_in[3];
    const float* U3_0  = (const float*)d_in[4];
    const float* W1_0  = (const float*)d_in[5];
    const float* W2_0  = (const float*)d_in[6];
    const float* W3_0  = (const float*)d_in[7];
    const float* Wl_0  = (const float*)d_in[8];
    const float* U1_1  = (const float*)d_in[9];
    const float* U2_1  = (const float*)d_in[10];
    const float* U3_1  = (const float*)d_in[11];
    const float* W1_1  = (const float*)d_in[12];
    const float* W2_1  = (const float*)d_in[13];
    const float* W3_1  = (const float*)d_in[14];
    const float* Wl_1  = (const float*)d_in[15];

    char* ws = (char*)d_ws;
    int*    nodelist = (int*)(ws + NL_OFF);
    int*    counts   = (int*)(ws + CNT_OFF);
    float4* call4    = (float4*)(ws + CALL_OFF);
    float*  uhat     = (float*)(ws + UHAT_OFF);
    float4* fbuf     = (float4*)(ws + F_OFF);

    k_usym3<<<dim3(64), dim3(256), 0, stream>>>(U3_0, U3_1, uhat);
    k_usym2lin<<<dim3(5), dim3(256), 0, stream>>>(U2_0, U2_1, U1_0, U1_1, uhat);
    k_plist<<<dim3(1), dim3(1024), 0, stream>>>(spec, nodelist, counts);
    k_fold<<<dim3(440), dim3(256), 0, stream>>>(uhat, W1_0, W2_0, W3_0,
                                                W1_1, W2_1, W3_1, call4);
    k_eval<<<dim3(1280), dim3(256), 0, stream>>>(x, nodelist, counts, call4, fbuf);
    k_linear<<<dim3(512), dim3(256), 0, stream>>>(fbuf, Wl_0, Wl_1, (float*)d_out);
}

// Round 5
// 88.390 us; speedup vs baseline: 4.0448x; 1.2920x over previous
//
#include <hip/hip_runtime.h>

typedef float v2f __attribute__((ext_vector_type(2)));

// ---------------- problem constants ----------------
#define NN    1024
#define CC    128
#define NELEM 10
#define NQ3   816
#define NQ2   136
#define NQ    968
#define KP    48     // unified p-dim: 30 (w3) + 12 (w2) + 4 (w1) + 2 pad
#define QT    22     // q-tile per fold block (44 tiles)

// ---------------- workspace layout (bytes) ----------------
#define NL_OFF    0          // int[10][1024] = 40960
#define CNT_OFF   40960      // int[10]
#define CALL_OFF  524288     // float4[1280][968] = 19824640 -> 20348928
#define F_OFF     20447232   // float4[1024][128] = 2097152  -> 22544384
#define UHAT_OFF  20447232   // float[4][968][48] = 743424 (aliases F; dead before k_eval)

__device__ __constant__ int d_OFF2[16] = {0,16,31,45,58,70,81,91,100,108,115,121,126,130,133,135};
__device__ __constant__ int d_OFF3[16] = {0,136,256,361,452,530,596,651,696,732,760,781,796,806,812,815};

// ---- build symmetrized cubic rows of Uhat: q in [0,816), p[0..29] = sym3, rest 0 ----
__global__ void k_usym3(const float* __restrict__ U3_0, const float* __restrict__ U3_1,
                        float* __restrict__ uhat) {
    int tid = blockIdx.x * 256 + threadIdx.x;
    if (tid >= 4 * 4096) return;
    int Lout = tid >> 12;
    int r = tid & 4095;
    int a = r >> 8, b = (r >> 4) & 15, m = r & 15;
    if (a > b || b > m) return;
    int q = d_OFF3[a] + (d_OFF2[b] - d_OFF2[a]) + (m - b);
    const float* U = (Lout == 0) ? U3_0 : U3_1;
    int L = (Lout == 0) ? 0 : (Lout - 1);
    int P[6][3] = {{a,b,m},{a,m,b},{b,a,m},{b,m,a},{m,a,b},{m,b,a}};
    float s[30];
#pragma unroll
    for (int p = 0; p < 30; ++p) s[p] = 0.f;
    for (int t = 0; t < 6; ++t) {
        bool dup = false;
        for (int u = 0; u < t; ++u)
            if (P[u][0] == P[t][0] && P[u][1] == P[t][1] && P[u][2] == P[t][2]) dup = true;
        if (dup) continue;
        const float* src = U + ((((L * 16 + P[t][0]) * 16 + P[t][1]) * 16 + P[t][2]) * 30);
#pragma unroll
        for (int p = 0; p < 30; ++p) s[p] += src[p];
    }
    float* dst = uhat + ((size_t)Lout * NQ + q) * KP;
#pragma unroll
    for (int p = 0; p < 30; ++p) dst[p] = s[p];
#pragma unroll
    for (int p = 30; p < KP; ++p) dst[p] = 0.f;
}

// ---- quad rows (q in [816,952), p[30..41]) + linear rows (q in [952,968), p[42..45]) ----
__global__ void k_usym2lin(const float* __restrict__ U2_0, const float* __restrict__ U2_1,
                           const float* __restrict__ U1_0, const float* __restrict__ U1_1,
                           float* __restrict__ uhat) {
    int tid = blockIdx.x * 256 + threadIdx.x;
    if (tid < 1024) {
        int Lout = tid >> 8;
        int r = tid & 255;
        int a = r >> 4, b = r & 15;
        if (a > b) return;
        int q = NQ3 + d_OFF2[a] + (b - a);
        const float* U = (Lout == 0) ? U2_0 : U2_1;
        int L = (Lout == 0) ? 0 : (Lout - 1);
        float* dst = uhat + ((size_t)Lout * NQ + q) * KP;
#pragma unroll
        for (int p = 0; p < 30; ++p) dst[p] = 0.f;
#pragma unroll
        for (int p = 0; p < 12; ++p) {
            float v = U[((L * 16 + a) * 16 + b) * 12 + p];
            if (a != b) v += U[((L * 16 + b) * 16 + a) * 12 + p];
            dst[30 + p] = v;
        }
#pragma unroll
        for (int p = 42; p < KP; ++p) dst[p] = 0.f;
    } else if (tid < 1024 + 64) {
        int s2 = tid - 1024;
        int Lout = s2 >> 4, i = s2 & 15;
        int q = NQ3 + NQ2 + i;
        const float* U = (Lout == 0) ? U1_0 : U1_1;
        int L = (Lout == 0) ? 0 : (Lout - 1);
        float* dst = uhat + ((size_t)Lout * NQ + q) * KP;
#pragma unroll
        for (int p = 0; p < 42; ++p) dst[p] = 0.f;
#pragma unroll
        for (int p = 0; p < 4; ++p) dst[42 + p] = U[(L * 16 + i) * 4 + p];
        dst[46] = 0.f; dst[47] = 0.f;
    }
}

// ---- per-species node lists ----
__global__ void k_plist(const int* __restrict__ species, int* __restrict__ nodelist,
                        int* __restrict__ counts) {
    __shared__ int cnt[NELEM];
    int t = threadIdx.x;
    if (t < NELEM) cnt[t] = 0;
    __syncthreads();
    int e = species[t];
    int pos = atomicAdd(&cnt[e], 1);
    nodelist[e * NN + pos] = t;
    __syncthreads();
    if (t < NELEM) counts[t] = cnt[t];
}

// ---- fold: call4[ec][q].L = dot48(Uhat[L][q][:], Wcat[Lg][:]) ----
// block = (e, q-tile of QT); Uhat tile staged in LDS; reads are wave-uniform ds_read_b128
__global__ __launch_bounds__(256) void k_fold(
    const float* __restrict__ uhat,
    const float* __restrict__ W1_0, const float* __restrict__ W2_0, const float* __restrict__ W3_0,
    const float* __restrict__ W1_1, const float* __restrict__ W2_1, const float* __restrict__ W3_1,
    float4* __restrict__ call4) {
    __shared__ __align__(16) float uh_lds[4][QT][KP];   // 16896 B
    int e  = blockIdx.x / 44;
    int qt = blockIdx.x % 44;
    int t = threadIdx.x;
    // stage Uhat tile: 4L x QT x 12 float4 = 1056 float4, coalesced
    {
        const float4* src4 = (const float4*)uhat;
        float4* dst4 = (float4*)uh_lds;
        for (int i = t; i < 4 * QT * 12; i += 256) {
            int l = i / (QT * 12);
            int r = i - l * (QT * 12);
            int qloc = r / 12, p4 = r % 12;
            dst4[i] = src4[((size_t)l * NQ + qt * QT + qloc) * 12 + p4];
        }
    }
    int c  = t & 127;
    int qs = t >> 7;
    float wr[2][KP];
#pragma unroll
    for (int p = 0; p < 30; ++p) {
        wr[0][p] = W3_0[(e * 30 + p) * CC + c];
        wr[1][p] = W3_1[(e * 30 + p) * CC + c];
    }
#pragma unroll
    for (int p = 0; p < 12; ++p) {
        wr[0][30 + p] = W2_0[(e * 12 + p) * CC + c];
        wr[1][30 + p] = W2_1[(e * 12 + p) * CC + c];
    }
#pragma unroll
    for (int p = 0; p < 4; ++p) {
        wr[0][42 + p] = W1_0[(e * 4 + p) * CC + c];
        wr[1][42 + p] = W1_1[(e * 4 + p) * CC + c];
    }
    wr[0][46] = wr[0][47] = wr[1][46] = wr[1][47] = 0.f;
    __syncthreads();
    size_t base = ((size_t)e * CC + c) * NQ;
    for (int j = 0; j < 11; ++j) {
        int qloc = qs * 11 + j;
        int q = qt * QT + qloc;
        float r[4];
#pragma unroll
        for (int l = 0; l < 4; ++l) {
            const float4* up = (const float4*)uh_lds[l][qloc];
            const float* w = (l == 0) ? wr[0] : wr[1];
            float acc0 = 0.f, acc1 = 0.f, acc2 = 0.f, acc3 = 0.f;
#pragma unroll
            for (int p4 = 0; p4 < 12; ++p4) {
                float4 u = up[p4];
                acc0 = fmaf(u.x, w[p4 * 4 + 0], acc0);
                acc1 = fmaf(u.y, w[p4 * 4 + 1], acc1);
                acc2 = fmaf(u.z, w[p4 * 4 + 2], acc2);
                acc3 = fmaf(u.w, w[p4 * 4 + 3], acc3);
            }
            r[l] = (acc0 + acc1) + (acc2 + acc3);
        }
        call4[base + q] = make_float4(r[0], r[1], r[2], r[3]);
    }
}

// ---- monomial macros (q pre-set to slice base; layout-lexicographic) ----
#define CUBIC(A0, A1) { \
    _Pragma("unroll") for (int a = (A0); a < (A1); ++a) { \
        _Pragma("unroll") for (int b = a; b < 16; ++b) { \
            v2f pab = xv[a] * xv[b]; \
            _Pragma("unroll") for (int m = b; m < 16; ++m) { \
                float4 w = cf_lds[q]; v2f mo = pab * xv[m]; \
                a0 += mo * w.x; a1 += mo * w.y; a2 += mo * w.z; a3 += mo * w.w; ++q; } } } }

#define QUAD(A0, A1) { \
    _Pragma("unroll") for (int a = (A0); a < (A1); ++a) { \
        _Pragma("unroll") for (int b = a; b < 16; ++b) { \
            float4 w = cf_lds[q]; v2f mo = xv[a] * xv[b]; \
            a0 += mo * w.x; a1 += mo * w.y; a2 += mo * w.z; a3 += mo * w.w; ++q; } } }

// ---- polynomial eval: block=(e,c); 4 wave-slices; 2 nodes/thread; pk-fp32 math ----
__global__ __launch_bounds__(256, 4) void k_eval(
    const float* __restrict__ x, const int* __restrict__ nodelist,
    const int* __restrict__ counts, const float4* __restrict__ call4,
    float4* __restrict__ fout) {
    __shared__ __align__(16) float4 cf_lds[NQ];      // 15488 B
    __shared__ __align__(16) v2f part[3][64][4];     // 6144 B
    int ec = blockIdx.x;
    int e = ec >> 7;
    int c = ec & 127;
    int cnt = counts[e];
    const float4* cf = call4 + (size_t)ec * NQ;
    int t = threadIdx.x;
    for (int i = t; i < NQ; i += 256) cf_lds[i] = cf[i];
    __syncthreads();
    int slice = t >> 6;
    int lane  = t & 63;

    for (int sb = 0; sb < cnt; sb += 128) {
        int i0 = sb + lane * 2, i1 = i0 + 1;
        bool v0i = i0 < cnt, v1i = i1 < cnt;
        int n0 = v0i ? nodelist[e * NN + i0] : 0;
        int n1 = v1i ? nodelist[e * NN + i1] : 0;
        const float4* xp0 = (const float4*)(x + ((size_t)n0 * CC + c) * 16);
        const float4* xp1 = (const float4*)(x + ((size_t)n1 * CC + c) * 16);
        float4 p0 = xp0[0], p1 = xp0[1], p2 = xp0[2], p3 = xp0[3];
        float4 q0 = xp1[0], q1 = xp1[1], q2 = xp1[2], q3 = xp1[3];
        v2f xv[16];
        xv[0]  = v2f{p0.x, q0.x}; xv[1]  = v2f{p0.y, q0.y};
        xv[2]  = v2f{p0.z, q0.z}; xv[3]  = v2f{p0.w, q0.w};
        xv[4]  = v2f{p1.x, q1.x}; xv[5]  = v2f{p1.y, q1.y};
        xv[6]  = v2f{p1.z, q1.z}; xv[7]  = v2f{p1.w, q1.w};
        xv[8]  = v2f{p2.x, q2.x}; xv[9]  = v2f{p2.y, q2.y};
        xv[10] = v2f{p2.z, q2.z}; xv[11] = v2f{p2.w, q2.w};
        xv[12] = v2f{p3.x, q3.x}; xv[13] = v2f{p3.y, q3.y};
        xv[14] = v2f{p3.z, q3.z}; xv[15] = v2f{p3.w, q3.w};
        if (!v0i) {
#pragma unroll
            for (int m = 0; m < 16; ++m) xv[m].x = 0.f;
        }
        if (!v1i) {
#pragma unroll
            for (int m = 0; m < 16; ++m) xv[m].y = 0.f;
        }
        v2f a0 = {0.f, 0.f}, a1 = {0.f, 0.f}, a2 = {0.f, 0.f}, a3 = {0.f, 0.f};
        int q;
        if (slice == 0) {            // cubic a=0..1 : q 0..255                (256)
            q = 0;   CUBIC(0, 2);
        } else if (slice == 1) {     // cubic a=2..3 + quad a=0..3             (254)
            q = 256; CUBIC(2, 4);
            q = NQ3; QUAD(0, 4);
        } else if (slice == 2) {     // cubic a=4..6 + quad a=4..9             (256)
            q = 452; CUBIC(4, 7);
            q = NQ3 + 58; QUAD(4, 10);
        } else {                     // cubic a=7..15 + quad a=10..15 + linear (202)
            q = 651; CUBIC(7, 16);
            q = NQ3 + 115; QUAD(10, 16);
            q = NQ3 + NQ2;
#pragma unroll
            for (int a = 0; a < 16; ++a) {
                float4 w = cf_lds[q]; v2f mo = xv[a];
                a0 += mo * w.x; a1 += mo * w.y; a2 += mo * w.z; a3 += mo * w.w; ++q;
            }
        }
        if (slice > 0) {
            part[slice - 1][lane][0] = a0; part[slice - 1][lane][1] = a1;
            part[slice - 1][lane][2] = a2; part[slice - 1][lane][3] = a3;
        }
        __syncthreads();
        if (slice == 0) {
            v2f s0 = a0 + part[0][lane][0] + part[1][lane][0] + part[2][lane][0];
            v2f s1 = a1 + part[0][lane][1] + part[1][lane][1] + part[2][lane][1];
            v2f s2 = a2 + part[0][lane][2] + part[1][lane][2] + part[2][lane][2];
            v2f s3 = a3 + part[0][lane][3] + part[1][lane][3] + part[2][lane][3];
            if (v0i) fout[(size_t)n0 * CC + c] = make_float4(s0.x, s1.x, s2.x, s3.x);
            if (v1i) fout[(size_t)n1 * CC + c] = make_float4(s0.y, s1.y, s2.y, s3.y);
        }
        __syncthreads();
    }
}

// ---- epilogue linear ----
__global__ __launch_bounds__(256) void k_linear(
    const float4* __restrict__ fin, const float* __restrict__ Wlin0,
    const float* __restrict__ Wlin1, float* __restrict__ out) {
    __shared__ float4 fl[256];
    int t = threadIdx.x;
    fl[t] = fin[(size_t)blockIdx.x * 256 + t];
    __syncthreads();
    int nl = t >> 7, k = t & 127;
    int n = blockIdx.x * 2 + nl;
    float a0 = 0.f, a1 = 0.f, a2 = 0.f, a3 = 0.f;
#pragma unroll 8
    for (int c = 0; c < CC; ++c) {
        float4 f = fl[nl * CC + c];
        float w0 = Wlin0[c * CC + k];
        float w1 = Wlin1[c * CC + k];
        a0 = fmaf(f.x, w0, a0);
        a1 = fmaf(f.y, w1, a1);
        a2 = fmaf(f.z, w1, a2);
        a3 = fmaf(f.w, w1, a3);
    }
    const float s = 0.08838834764831845f; // 1/sqrt(128)
    float* o = out + (size_t)n * 512;
    o[k] = a0 * s;
    o[128 + 3 * k + 0] = a1 * s;
    o[128 + 3 * k + 1] = a2 * s;
    o[128 + 3 * k + 2] = a3 * s;
}

extern "C" void kernel_launch(void* const* d_in, const int* in_sizes, int n_in,
                              void* d_out, int out_size, void* d_ws, size_t ws_size,
                              hipStream_t stream) {
    const float* x     = (const float*)d_in[0];
    const int*   spec  = (const int*)d_in[1];
    const float* U1_0  = (const float*)d_in[2];
    const float* U2_0  = (const float*)d_in[3];
    const float* U3_0  = (const float*)d_in[4];
    const float* W1_0  = (const float*)d_in[5];
    const float* W2_0  = (const float*)d_in[6];
    const float* W3_0  = (const float*)d_in[7];
    const float* Wl_0  = (const float*)d_in[8];
    const float* U1_1  = (const float*)d_in[9];
    const float* U2_1  = (const float*)d_in[10];
    const float* U3_1  = (const float*)d_in[11];
    const float* W1_1  = (const float*)d_in[12];
    const float* W2_1  = (const float*)d_in[13];
    const float* W3_1  = (const float*)d_in[14];
    const float* Wl_1  = (const float*)d_in[15];

    char* ws = (char*)d_ws;
    int*    nodelist = (int*)(ws + NL_OFF);
    int*    counts   = (int*)(ws + CNT_OFF);
    float4* call4    = (float4*)(ws + CALL_OFF);
    float*  uhat     = (float*)(ws + UHAT_OFF);
    float4* fbuf     = (float4*)(ws + F_OFF);

    k_usym3<<<dim3(64), dim3(256), 0, stream>>>(U3_0, U3_1, uhat);
    k_usym2lin<<<dim3(5), dim3(256), 0, stream>>>(U2_0, U2_1, U1_0, U1_1, uhat);
    k_plist<<<dim3(1), dim3(1024), 0, stream>>>(spec, nodelist, counts);
    k_fold<<<dim3(440), dim3(256), 0, stream>>>(uhat, W1_0, W2_0, W3_0,
                                                W1_1, W2_1, W3_1, call4);
    k_eval<<<dim3(1280), dim3(256), 0, stream>>>(x, nodelist, counts, call4, fbuf);
    k_linear<<<dim3(512), dim3(256), 0, stream>>>(fbuf, Wl_0, Wl_1, (float*)d_out);
}

// Round 6
// 75.128 us; speedup vs baseline: 4.7588x; 1.1765x over previous
//
#include <hip/hip_runtime.h>
#include <hip/hip_fp16.h>

typedef float v2f __attribute__((ext_vector_type(2)));

// ---------------- problem constants ----------------
#define NN    1024
#define CC    128
#define NELEM 10
#define NQ3   816
#define NQ2   136
#define NQ    968
#define KP    48     // unified p-dim: 30 (w3) + 12 (w2) + 4 (w1) + 2 pad
#define QT    11     // q-tile per fold block (88 tiles per e)
#define NTILE 88

// ---------------- workspace layout (bytes) ----------------
#define NL_OFF    0          // int[10][1024] = 40960
#define CNT_OFF   40960      // int[10]
#define CALL_OFF  524288     // half4[1280][968] = 9912320 -> 10436608
#define F_OFF     20447232   // float4[1024][128] = 2097152 -> 22544384
#define UHAT_OFF  10485760   // float[4][968][48] = 743424 (dead before k_eval)

__device__ __constant__ int d_OFF2[16] = {0,16,31,45,58,70,81,91,100,108,115,121,126,130,133,135};
__device__ __constant__ int d_OFF3[16] = {0,136,256,361,452,530,596,651,696,732,760,781,796,806,812,815};

// ---- build Uhat rows: blocks 0..63 = sym3, blocks 64..68 = sym2 + linear ----
__global__ void k_usym(const float* __restrict__ U3_0, const float* __restrict__ U3_1,
                       const float* __restrict__ U2_0, const float* __restrict__ U2_1,
                       const float* __restrict__ U1_0, const float* __restrict__ U1_1,
                       float* __restrict__ uhat) {
    if (blockIdx.x < 64) {
        int tid = blockIdx.x * 256 + threadIdx.x;
        int Lout = tid >> 12;
        int r = tid & 4095;
        int a = r >> 8, b = (r >> 4) & 15, m = r & 15;
        if (a > b || b > m) return;
        int q = d_OFF3[a] + (d_OFF2[b] - d_OFF2[a]) + (m - b);
        const float* U = (Lout == 0) ? U3_0 : U3_1;
        int L = (Lout == 0) ? 0 : (Lout - 1);
        int P[6][3] = {{a,b,m},{a,m,b},{b,a,m},{b,m,a},{m,a,b},{m,b,a}};
        float s[30];
#pragma unroll
        for (int p = 0; p < 30; ++p) s[p] = 0.f;
        for (int t = 0; t < 6; ++t) {
            bool dup = false;
            for (int u = 0; u < t; ++u)
                if (P[u][0] == P[t][0] && P[u][1] == P[t][1] && P[u][2] == P[t][2]) dup = true;
            if (dup) continue;
            const float* src = U + ((((L * 16 + P[t][0]) * 16 + P[t][1]) * 16 + P[t][2]) * 30);
#pragma unroll
            for (int p = 0; p < 30; ++p) s[p] += src[p];
        }
        float* dst = uhat + ((size_t)Lout * NQ + q) * KP;
#pragma unroll
        for (int p = 0; p < 30; ++p) dst[p] = s[p];
#pragma unroll
        for (int p = 30; p < KP; ++p) dst[p] = 0.f;
    } else {
        int tid = (blockIdx.x - 64) * 256 + threadIdx.x;
        if (tid < 1024) {
            int Lout = tid >> 8;
            int r = tid & 255;
            int a = r >> 4, b = r & 15;
            if (a > b) return;
            int q = NQ3 + d_OFF2[a] + (b - a);
            const float* U = (Lout == 0) ? U2_0 : U2_1;
            int L = (Lout == 0) ? 0 : (Lout - 1);
            float* dst = uhat + ((size_t)Lout * NQ + q) * KP;
#pragma unroll
            for (int p = 0; p < 30; ++p) dst[p] = 0.f;
#pragma unroll
            for (int p = 0; p < 12; ++p) {
                float v = U[((L * 16 + a) * 16 + b) * 12 + p];
                if (a != b) v += U[((L * 16 + b) * 16 + a) * 12 + p];
                dst[30 + p] = v;
            }
#pragma unroll
            for (int p = 42; p < KP; ++p) dst[p] = 0.f;
        } else if (tid < 1024 + 64) {
            int s2 = tid - 1024;
            int Lout = s2 >> 4, i = s2 & 15;
            int q = NQ3 + NQ2 + i;
            const float* U = (Lout == 0) ? U1_0 : U1_1;
            int L = (Lout == 0) ? 0 : (Lout - 1);
            float* dst = uhat + ((size_t)Lout * NQ + q) * KP;
#pragma unroll
            for (int p = 0; p < 42; ++p) dst[p] = 0.f;
#pragma unroll
            for (int p = 0; p < 4; ++p) dst[42 + p] = U[(L * 16 + i) * 4 + p];
            dst[46] = 0.f; dst[47] = 0.f;
        }
    }
}

// ---- per-species node lists ----
__global__ void k_plist(const int* __restrict__ species, int* __restrict__ nodelist,
                        int* __restrict__ counts) {
    __shared__ int cnt[NELEM];
    int t = threadIdx.x;
    if (t < NELEM) cnt[t] = 0;
    __syncthreads();
    int e = species[t];
    int pos = atomicAdd(&cnt[e], 1);
    nodelist[e * NN + pos] = t;
    __syncthreads();
    if (t < NELEM) counts[t] = cnt[t];
}

// ---- fold: call4h[ec][q] = half4{ dot48(Uhat[L][q][:], Wcat[Lg][:]) for L=0..3 } ----
__global__ __launch_bounds__(256) void k_fold(
    const float* __restrict__ uhat,
    const float* __restrict__ W1_0, const float* __restrict__ W2_0, const float* __restrict__ W3_0,
    const float* __restrict__ W1_1, const float* __restrict__ W2_1, const float* __restrict__ W3_1,
    uint2* __restrict__ call4h) {
    __shared__ __align__(16) float uh_lds[4][QT][KP];   // 8448 B
    int e  = blockIdx.x / NTILE;
    int qt = blockIdx.x % NTILE;
    int t = threadIdx.x;
    // stage Uhat tile: 4L x QT x 12 float4 = 528 float4, coalesced
    {
        const float4* src4 = (const float4*)uhat;
        float4* dst4 = (float4*)uh_lds;
        for (int i = t; i < 4 * QT * 12; i += 256) {
            int l = i / (QT * 12);
            int r = i - l * (QT * 12);
            int qloc = r / 12, p4 = r % 12;
            dst4[i] = src4[((size_t)l * NQ + qt * QT + qloc) * 12 + p4];
        }
    }
    int c  = t & 127;
    int qs = t >> 7;
    float wr[2][KP];
#pragma unroll
    for (int p = 0; p < 30; ++p) {
        wr[0][p] = W3_0[(e * 30 + p) * CC + c];
        wr[1][p] = W3_1[(e * 30 + p) * CC + c];
    }
#pragma unroll
    for (int p = 0; p < 12; ++p) {
        wr[0][30 + p] = W2_0[(e * 12 + p) * CC + c];
        wr[1][30 + p] = W2_1[(e * 12 + p) * CC + c];
    }
#pragma unroll
    for (int p = 0; p < 4; ++p) {
        wr[0][42 + p] = W1_0[(e * 4 + p) * CC + c];
        wr[1][42 + p] = W1_1[(e * 4 + p) * CC + c];
    }
    wr[0][46] = wr[0][47] = wr[1][46] = wr[1][47] = 0.f;
    __syncthreads();
    size_t base = ((size_t)e * CC + c) * NQ;
    for (int j = 0; j < 6; ++j) {
        int qloc = qs * 6 + j;
        if (qloc >= QT) break;
        int q = qt * QT + qloc;
        float r[4];
#pragma unroll
        for (int l = 0; l < 4; ++l) {
            const float4* up = (const float4*)uh_lds[l][qloc];
            const float* w = (l == 0) ? wr[0] : wr[1];
            float acc0 = 0.f, acc1 = 0.f, acc2 = 0.f, acc3 = 0.f;
#pragma unroll
            for (int p4 = 0; p4 < 12; ++p4) {
                float4 u = up[p4];
                acc0 = fmaf(u.x, w[p4 * 4 + 0], acc0);
                acc1 = fmaf(u.y, w[p4 * 4 + 1], acc1);
                acc2 = fmaf(u.z, w[p4 * 4 + 2], acc2);
                acc3 = fmaf(u.w, w[p4 * 4 + 3], acc3);
            }
            r[l] = (acc0 + acc1) + (acc2 + acc3);
        }
        __half2 h01 = __floats2half2_rn(r[0], r[1]);
        __half2 h23 = __floats2half2_rn(r[2], r[3]);
        uint2 v;
        v.x = *(unsigned int*)&h01;
        v.y = *(unsigned int*)&h23;
        call4h[base + q] = v;
    }
}

// ---- monomial macros: f16 coeff unpack + pk-fp32 fma ----
#define COEF(W0, W1, W2, W3) \
    uint2 pk = cf_lds[q]; \
    __half2 h01 = *(__half2*)&pk.x; __half2 h23 = *(__half2*)&pk.y; \
    float W0 = __half2float(h01.x), W1 = __half2float(h01.y); \
    float W2 = __half2float(h23.x), W3 = __half2float(h23.y);

#define CUBIC(A0, A1) { \
    _Pragma("unroll") for (int a = (A0); a < (A1); ++a) { \
        _Pragma("unroll") for (int b = a; b < 16; ++b) { \
            v2f pab = xv[a] * xv[b]; \
            _Pragma("unroll") for (int m = b; m < 16; ++m) { \
                COEF(wx, wy, wz, ww); v2f mo = pab * xv[m]; \
                a0 += mo * wx; a1 += mo * wy; a2 += mo * wz; a3 += mo * ww; ++q; } } } }

#define QUAD(A0, A1) { \
    _Pragma("unroll") for (int a = (A0); a < (A1); ++a) { \
        _Pragma("unroll") for (int b = a; b < 16; ++b) { \
            COEF(wx, wy, wz, ww); v2f mo = xv[a] * xv[b]; \
            a0 += mo * wx; a1 += mo * wy; a2 += mo * wz; a3 += mo * ww; ++q; } } }

// ---- polynomial eval: block=(e,c); 4 wave-slices; 2 nodes/thread; pk-fp32 math ----
__global__ __launch_bounds__(256) void k_eval(
    const float* __restrict__ x, const int* __restrict__ nodelist,
    const int* __restrict__ counts, const uint2* __restrict__ call4h,
    float4* __restrict__ fout) {
    __shared__ __align__(16) uint2 cf_lds[NQ];       // 7744 B
    __shared__ __align__(16) v2f part[3][64][4];     // 6144 B
    int ec = blockIdx.x;
    int e = ec >> 7;
    int c = ec & 127;
    int cnt = counts[e];
    const float4* cf4 = (const float4*)(call4h + (size_t)ec * NQ);
    int t = threadIdx.x;
    int slice = t >> 6;
    int lane  = t & 63;

    // issue first-pass node/x loads BEFORE staging so vmem overlaps
    int i0 = lane * 2, i1 = i0 + 1;
    bool v0i = i0 < cnt, v1i = i1 < cnt;
    int n0 = v0i ? nodelist[e * NN + i0] : 0;
    int n1 = v1i ? nodelist[e * NN + i1] : 0;

    // stage coefficients (coalesced float4 = 2 q each)
    for (int i = t; i < NQ / 2; i += 256) ((float4*)cf_lds)[i] = cf4[i];

    for (int sb = 0; sb < cnt; sb += 128) {
        if (sb > 0) {
            i0 = sb + lane * 2; i1 = i0 + 1;
            v0i = i0 < cnt; v1i = i1 < cnt;
            n0 = v0i ? nodelist[e * NN + i0] : 0;
            n1 = v1i ? nodelist[e * NN + i1] : 0;
        }
        const float4* xp0 = (const float4*)(x + ((size_t)n0 * CC + c) * 16);
        const float4* xp1 = (const float4*)(x + ((size_t)n1 * CC + c) * 16);
        float4 p0 = xp0[0], p1 = xp0[1], p2 = xp0[2], p3 = xp0[3];
        float4 q0 = xp1[0], q1 = xp1[1], q2 = xp1[2], q3 = xp1[3];
        if (sb == 0) __syncthreads();   // staging visible before cf_lds reads
        v2f xv[16];
        xv[0]  = v2f{p0.x, q0.x}; xv[1]  = v2f{p0.y, q0.y};
        xv[2]  = v2f{p0.z, q0.z}; xv[3]  = v2f{p0.w, q0.w};
        xv[4]  = v2f{p1.x, q1.x}; xv[5]  = v2f{p1.y, q1.y};
        xv[6]  = v2f{p1.z, q1.z}; xv[7]  = v2f{p1.w, q1.w};
        xv[8]  = v2f{p2.x, q2.x}; xv[9]  = v2f{p2.y, q2.y};
        xv[10] = v2f{p2.z, q2.z}; xv[11] = v2f{p2.w, q2.w};
        xv[12] = v2f{p3.x, q3.x}; xv[13] = v2f{p3.y, q3.y};
        xv[14] = v2f{p3.z, q3.z}; xv[15] = v2f{p3.w, q3.w};
        if (!v0i) {
#pragma unroll
            for (int m = 0; m < 16; ++m) xv[m].x = 0.f;
        }
        if (!v1i) {
#pragma unroll
            for (int m = 0; m < 16; ++m) xv[m].y = 0.f;
        }
        v2f a0 = {0.f, 0.f}, a1 = {0.f, 0.f}, a2 = {0.f, 0.f}, a3 = {0.f, 0.f};
        int q;
        if (slice == 0) {            // cubic a=0..1 : q 0..255                (256)
            q = 0;   CUBIC(0, 2);
        } else if (slice == 1) {     // cubic a=2..3 + quad a=0..3             (254)
            q = 256; CUBIC(2, 4);
            q = NQ3; QUAD(0, 4);
        } else if (slice == 2) {     // cubic a=4..6 + quad a=4..9             (256)
            q = 452; CUBIC(4, 7);
            q = NQ3 + 58; QUAD(4, 10);
        } else {                     // cubic a=7..15 + quad a=10..15 + linear (202)
            q = 651; CUBIC(7, 16);
            q = NQ3 + 115; QUAD(10, 16);
            q = NQ3 + NQ2;
#pragma unroll
            for (int a = 0; a < 16; ++a) {
                COEF(wx, wy, wz, ww); v2f mo = xv[a];
                a0 += mo * wx; a1 += mo * wy; a2 += mo * wz; a3 += mo * ww; ++q;
            }
        }
        if (slice > 0) {
            part[slice - 1][lane][0] = a0; part[slice - 1][lane][1] = a1;
            part[slice - 1][lane][2] = a2; part[slice - 1][lane][3] = a3;
        }
        __syncthreads();
        if (slice == 0) {
            v2f s0 = a0 + part[0][lane][0] + part[1][lane][0] + part[2][lane][0];
            v2f s1 = a1 + part[0][lane][1] + part[1][lane][1] + part[2][lane][1];
            v2f s2 = a2 + part[0][lane][2] + part[1][lane][2] + part[2][lane][2];
            v2f s3 = a3 + part[0][lane][3] + part[1][lane][3] + part[2][lane][3];
            if (v0i) fout[(size_t)n0 * CC + c] = make_float4(s0.x, s1.x, s2.x, s3.x);
            if (v1i) fout[(size_t)n1 * CC + c] = make_float4(s0.y, s1.y, s2.y, s3.y);
        }
        __syncthreads();
    }
}

// ---- epilogue linear ----
__global__ __launch_bounds__(256) void k_linear(
    const float4* __restrict__ fin, const float* __restrict__ Wlin0,
    const float* __restrict__ Wlin1, float* __restrict__ out) {
    __shared__ float4 fl[256];
    int t = threadIdx.x;
    fl[t] = fin[(size_t)blockIdx.x * 256 + t];
    __syncthreads();
    int nl = t >> 7, k = t & 127;
    int n = blockIdx.x * 2 + nl;
    float a0 = 0.f, a1 = 0.f, a2 = 0.f, a3 = 0.f;
#pragma unroll 8
    for (int c = 0; c < CC; ++c) {
        float4 f = fl[nl * CC + c];
        float w0 = Wlin0[c * CC + k];
        float w1 = Wlin1[c * CC + k];
        a0 = fmaf(f.x, w0, a0);
        a1 = fmaf(f.y, w1, a1);
        a2 = fmaf(f.z, w1, a2);
        a3 = fmaf(f.w, w1, a3);
    }
    const float s = 0.08838834764831845f; // 1/sqrt(128)
    float* o = out + (size_t)n * 512;
    o[k] = a0 * s;
    o[128 + 3 * k + 0] = a1 * s;
    o[128 + 3 * k + 1] = a2 * s;
    o[128 + 3 * k + 2] = a3 * s;
}

extern "C" void kernel_launch(void* const* d_in, const int* in_sizes, int n_in,
                              void* d_out, int out_size, void* d_ws, size_t ws_size,
                              hipStream_t stream) {
    const float* x     = (const float*)d_in[0];
    const int*   spec  = (const int*)d_in[1];
    const float* U1_0  = (const float*)d_in[2];
    const float* U2_0  = (const float*)d_in[3];
    const float* U3_0  = (const float*)d_in[4];
    const float* W1_0  = (const float*)d_in[5];
    const float* W2_0  = (const float*)d_in[6];
    const float* W3_0  = (const float*)d_in[7];
    const float* Wl_0  = (const float*)d_in[8];
    const float* U1_1  = (const float*)d_in[9];
    const float* U2_1  = (const float*)d_in[10];
    const float* U3_1  = (const float*)d_in[11];
    const float* W1_1  = (const float*)d_in[12];
    const float* W2_1  = (const float*)d_in[13];
    const float* W3_1  = (const float*)d_in[14];
    const float* Wl_1  = (const float*)d_in[15];

    char* ws = (char*)d_ws;
    int*    nodelist = (int*)(ws + NL_OFF);
    int*    counts   = (int*)(ws + CNT_OFF);
    uint2*  call4h   = (uint2*)(ws + CALL_OFF);
    float*  uhat     = (float*)(ws + UHAT_OFF);
    float4* fbuf     = (float4*)(ws + F_OFF);

    k_usym<<<dim3(69), dim3(256), 0, stream>>>(U3_0, U3_1, U2_0, U2_1, U1_0, U1_1, uhat);
    k_plist<<<dim3(1), dim3(1024), 0, stream>>>(spec, nodelist, counts);
    k_fold<<<dim3(880), dim3(256), 0, stream>>>(uhat, W1_0, W2_0, W3_0,
                                                W1_1, W2_1, W3_1, call4h);
    k_eval<<<dim3(1280), dim3(256), 0, stream>>>(x, nodelist, counts, call4h, fbuf);
    k_linear<<<dim3(512), dim3(256), 0, stream>>>(fbuf, Wl_0, Wl_1, (float*)d_out);
}